// Round 4
// baseline (110.949 us; speedup 1.0000x reference)
//
#include <hip/hip_runtime.h>
#include <hip/hip_bf16.h>

#define Tn 4096
#define Cn 768
#define Hn 12
#define DHn 64
#define BAND 192
#define QBLK 64
#define TJ 256        // BAND + QBLK staged keys per block
#define NTW 13        // 16-key tiles per wave (band window)

typedef __attribute__((ext_vector_type(8))) short short8;
typedef __attribute__((ext_vector_type(4))) short short4v;
typedef __attribute__((ext_vector_type(4))) float f32x4;

__device__ __forceinline__ float b2f(unsigned short u) {
  union { unsigned int i; float f; } z; z.i = ((unsigned int)u) << 16; return z.f;
}
__device__ __forceinline__ unsigned short f2b(float f) {
  union { float f; unsigned int i; } z; z.f = f;
  unsigned int r = z.i + 0x7FFFu + ((z.i >> 16) & 1u);
  return (unsigned short)(r >> 16);
}

// ---------------- prep: f32->bf16 convert + both weight transposes, one kernel ----------------
// blocks [0,512): convert x; [512,2240): Wqkv transpose (72x24 tiles); [2240,2816): Wproj (24x24)
__global__ __launch_bounds__(256) void k_prep(const float* __restrict__ x,
                                              unsigned short* __restrict__ x_bf,
                                              const float* __restrict__ Wqkv,
                                              unsigned short* __restrict__ WqkvT,
                                              const float* __restrict__ Wproj,
                                              unsigned short* __restrict__ WprojT) {
  __shared__ float tile[32][33];
  int b = blockIdx.x, tid = threadIdx.x;
  if (b < 512) {
    int n4 = Tn * Cn / 4;
    for (int i = b * 256 + tid; i < n4; i += 512 * 256) {
      float4 v = ((const float4*)x)[i];
      short4v o;
      o.x = (short)f2b(v.x); o.y = (short)f2b(v.y);
      o.z = (short)f2b(v.z); o.w = (short)f2b(v.w);
      ((short4v*)x_bf)[i] = o;
    }
    return;
  }
  const float* W; unsigned short* WT; int N, r;
  if (b < 2240) { r = b - 512; W = Wqkv; WT = WqkvT; N = 3 * Cn; }
  else          { r = b - 2240; W = Wproj; WT = WprojT; N = Cn; }
  int nb = N / 32;
  int n0 = (r % nb) * 32, k0 = (r / nb) * 32;
  int tx = tid & 31, ty = tid >> 5;   // 32 x 8
  for (int rr = ty; rr < 32; rr += 8) tile[rr][tx] = W[(size_t)(k0 + rr) * N + n0 + tx];
  __syncthreads();
  for (int rr = ty; rr < 32; rr += 8) WT[(size_t)(n0 + rr) * Cn + k0 + tx] = f2b(tile[tx][rr]);
}

// ---------------- bf16 MFMA GEMM: C[M,N] = A[M,K] * BT[N,K]^T ----------------
// EPI==1: f32 output to Cout. EPI==2: fused RoPE + head-split epilogue
// (writes q_r/k_r/v_s [H][T][64] bf16; N must be 2304 = q|k|v).
template<int EPI>
__global__ __launch_bounds__(256) void k_gemm_bt(const unsigned short* __restrict__ A,
                                                 const unsigned short* __restrict__ BT,
                                                 void* __restrict__ Cout,
                                                 int M, int N, int K,
                                                 const float* __restrict__ cosT,
                                                 const float* __restrict__ sinT,
                                                 unsigned short* __restrict__ qout,
                                                 unsigned short* __restrict__ kout,
                                                 unsigned short* __restrict__ vout) {
  __shared__ unsigned short As[128 * 32];
  __shared__ unsigned short Bs[128 * 32];
  int tid = threadIdx.x, lane = tid & 63, wave = tid >> 6;
  int wr = wave >> 1, wc = wave & 1;
  int m0 = blockIdx.y * 128, n0 = blockIdx.x * 128;
  f32x4 acc[4][4] = {};
  const unsigned short* Ab = A + (size_t)m0 * K;
  const unsigned short* Bb = BT + (size_t)n0 * K;
  int arow = (lane >> 2), acol = (lane & 3) * 8;
  for (int k0 = 0; k0 < K; k0 += 32) {
    __syncthreads();
#pragma unroll
    for (int u = 0; u < 2; ++u) {
      int s = wave * 2 + u;
      const unsigned short* ga = Ab + (size_t)(s * 16 + arow) * K + k0 + acol;
      const unsigned short* gb = Bb + (size_t)(s * 16 + arow) * K + k0 + acol;
      __builtin_amdgcn_global_load_lds((const __attribute__((address_space(1))) void*)ga,
                                       (__attribute__((address_space(3))) void*)(As + s * 512),
                                       16, 0, 0);
      __builtin_amdgcn_global_load_lds((const __attribute__((address_space(1))) void*)gb,
                                       (__attribute__((address_space(3))) void*)(Bs + s * 512),
                                       16, 0, 0);
    }
    __syncthreads();
    short8 a[4], b[4];
#pragma unroll
    for (int m = 0; m < 4; ++m)
      a[m] = *(const short8*)(As + (wr * 64 + m * 16 + (lane & 15)) * 32 + (lane >> 4) * 8);
#pragma unroll
    for (int n = 0; n < 4; ++n)
      b[n] = *(const short8*)(Bs + (wc * 64 + n * 16 + (lane & 15)) * 32 + (lane >> 4) * 8);
#pragma unroll
    for (int m = 0; m < 4; ++m)
#pragma unroll
      for (int n = 0; n < 4; ++n)
        acc[m][n] = __builtin_amdgcn_mfma_f32_16x16x32_bf16(a[m], b[n], acc[m][n], 0, 0, 0);
  }
  int lq = lane & 15;
  int r0 = m0 + wr * 64 + (lane >> 4) * 4;
  if (EPI == 1) {
    int c0 = n0 + wc * 64 + lq;
#pragma unroll
    for (int m = 0; m < 4; ++m)
#pragma unroll
      for (int n = 0; n < 4; ++n)
#pragma unroll
        for (int i = 0; i < 4; ++i)
          ((float*)Cout)[(size_t)(r0 + m * 16 + i) * N + c0 + n * 16] = acc[m][n][i];
  } else {
    // fused RoPE + split: this wave's 64 cols are exactly one head of q|k|v
    int col0 = n0 + wc * 64;
    int part = col0 / Cn;
    int h = (col0 % Cn) / DHn;
    unsigned short* dst = part == 0 ? qout : (part == 1 ? kout : vout);
    unsigned short* db = dst + (size_t)h * Tn * DHn;
#pragma unroll
    for (int m = 0; m < 4; ++m)
#pragma unroll
      for (int i = 0; i < 4; ++i) {
        int t = r0 + m * 16 + i;
#pragma unroll
        for (int n = 0; n < 4; ++n) {
          int d = n * 16 + lq;
          float val = acc[m][n][i];
          if (part < 2) {
            float cv = cosT[t * DHn + d], sv = sinT[t * DHn + d];
            float partner = acc[m][n ^ 2][i];
            val = (n < 2) ? fmaf(-partner, sv, val * cv) : fmaf(partner, sv, val * cv);
          }
          db[(size_t)t * DHn + d] = f2b(val);
        }
      }
  }
}

// ---- stage a 256x64 bf16 tile into LDS in 4x16-subtiled layout via global_load_lds ----
// LDS layout: addr(j,d) = (j>>2)*512 + (d>>4)*128 + (j&3)*32 + (d&15)*2   (bytes)
__device__ __forceinline__ void stage_subtiled(const unsigned short* __restrict__ srcHead,
                                               int jt0, unsigned short* lds, int tid, int wave) {
#pragma unroll
  for (int it = 0; it < 8; ++it) {
    int c = it * 256 + tid;                       // 16B chunk index
    int j = jt0 + ((c >> 5) << 2) + ((c & 7) >> 1);
    j = j < 0 ? 0 : j;
    int d0 = (((c >> 3) & 3) << 4) + ((c & 1) << 3);
    const unsigned short* ga = srcHead + (size_t)j * DHn + d0;
    __builtin_amdgcn_global_load_lds((const __attribute__((address_space(1))) void*)ga,
                                     (__attribute__((address_space(3))) void*)(lds + (it * 4 + wave) * 512),
                                     16, 0, 0);
  }
}

// ---- PV: 7 A-frags (P) x subtiled-V tile -> oacc[4] via ds_read_b64_tr_b16 ----
__device__ __forceinline__ void pv_tr(const unsigned short* Vt, const short8* af,
                                      int wave, int lane, f32x4* oacc) {
  int lq = lane & 15, g = lane >> 4;
  unsigned base = (unsigned)(size_t)(const __attribute__((address_space(3))) unsigned short*)Vt;
  unsigned pl = base + lq * 8;
#pragma unroll
  for (int e = 0; e < 7; ++e) {
    int kl = 16 * wave + 32 * e + 8 * g;
    if (kl > TJ - 8) kl = TJ - 8;          // those lanes carry p==0
    unsigned pe = pl + kl * 128;
    unsigned long long rr[8];
#pragma unroll
    for (int dt = 0; dt < 4; ++dt) {
      asm volatile("ds_read_b64_tr_b16 %0, %1" : "=v"(rr[2 * dt]) : "v"(pe + dt * 128));
      asm volatile("ds_read_b64_tr_b16 %0, %1" : "=v"(rr[2 * dt + 1]) : "v"(pe + dt * 128 + 512));
    }
    asm volatile("s_waitcnt lgkmcnt(0)");
    __builtin_amdgcn_sched_barrier(0);
#pragma unroll
    for (int dt = 0; dt < 4; ++dt) {
      union { unsigned long long u[2]; short8 s; } vb;
      vb.u[0] = rr[2 * dt]; vb.u[1] = rr[2 * dt + 1];
      oacc[dt] = __builtin_amdgcn_mfma_f32_16x16x32_bf16(af[e], vb.s, oacc[dt], 0, 0, 0);
    }
  }
}

// ---------------- pass A: QK^T + softmax; write pv1 and normalized P fragments ----------------
__global__ __launch_bounds__(256) void k_attn_a(const unsigned short* __restrict__ qr,
                                                const unsigned short* __restrict__ kr,
                                                const unsigned short* __restrict__ vin,
                                                unsigned short* __restrict__ pv1out,
                                                unsigned short* __restrict__ pfrag,
                                                const float* __restrict__ kap_p,
                                                const float* __restrict__ xi_p) {
  __shared__ unsigned short Ks[TJ * DHn];   // row-major, 16B-unit XOR swizzle per row
  __shared__ unsigned short Vt[TJ * DHn];   // 4x16 subtiled for tr_read
  int tid = threadIdx.x, lane = tid & 63, wave = tid >> 6;
  int lq = lane & 15, g = lane >> 4;
  int i0 = blockIdx.x * QBLK, h = blockIdx.y;
  int jt0 = i0 - BAND;
  const size_t headoff = (size_t)h * Tn * DHn;

  // stage K (swizzled rows, pre-swizzled global source)
  const unsigned short* krh = kr + headoff;
#pragma unroll
  for (int it = 0; it < 8; ++it) {
    int u = it * 256 + tid;
    int row = u >> 3, c8 = u & 7;
    int j = jt0 + row; j = j < 0 ? 0 : j;
    const unsigned short* ga = krh + (size_t)j * DHn + ((c8 ^ (row & 7)) << 3);
    __builtin_amdgcn_global_load_lds((const __attribute__((address_space(1))) void*)ga,
                                     (__attribute__((address_space(3))) void*)((char*)Ks + (size_t)(it * 256 + wave * 64) * 16),
                                     16, 0, 0);
  }
  // stage V subtiled
  stage_subtiled(vin + headoff, jt0, Vt, tid, wave);

  // Q fragments from global
  const unsigned short* qrh = qr + headoff;
  int q0 = i0 + wave * 16;
  short8 qf0 = *(const short8*)(qrh + (size_t)(q0 + lq) * DHn + g * 8);
  short8 qf1 = *(const short8*)(qrh + (size_t)(q0 + lq) * DHn + 32 + g * 8);
  __syncthreads();

  // S^T = K . Q^T over this wave's 13 key tiles
  f32x4 st[NTW];
#pragma unroll
  for (int t = 0; t < NTW; ++t) st[t] = (f32x4){0.f, 0.f, 0.f, 0.f};
#pragma unroll
  for (int t = 0; t < NTW; ++t) {
    int row = (wave + t) * 16 + lq;
    const char* kb = (const char*)Ks + row * 128;
    int sw = row & 7;
    short8 ka0 = *(const short8*)(kb + ((g ^ sw) << 4));
    short8 ka1 = *(const short8*)(kb + (((4 + g) ^ sw) << 4));
    st[t] = __builtin_amdgcn_mfma_f32_16x16x32_bf16(ka0, qf0, st[t], 0, 0, 0);
    st[t] = __builtin_amdgcn_mfma_f32_16x16x32_bf16(ka1, qf1, st[t], 0, 0, 0);
  }

  // softmax (log2 domain), lane-local + 2 shfl_xor
  float kap = log1pf(__expf(*kap_p));
  float xi  = log1pf(__expf(*xi_p));
  const float LOG2E = 1.4426950408889634f;
  float sc = 0.125f * LOG2E;
  float c2 = kap / (xi * xi) * LOG2E;
  float db0 = (float)(lq + BAND - 4 * g);
  float jb0 = (float)(jt0 + 16 * wave + 4 * g);
  float m = -3.0e38f;
#pragma unroll
  for (int t = 0; t < NTW; ++t) {
#pragma unroll
    for (int r = 0; r < 4; ++r) {
      float off = (float)(16 * t + r);
      float dist = db0 - off;
      float jv = jb0 + off;
      float l2 = fmaf(dist * dist, -c2, st[t][r] * sc);
      bool bad = (dist < 0.f) || (jv < 0.f);
      l2 = bad ? -3.0e38f : l2;
      st[t][r] = l2;
      m = fmaxf(m, l2);
    }
  }
  m = fmaxf(m, __shfl_xor(m, 16));
  m = fmaxf(m, __shfl_xor(m, 32));
  float sum = 0.f;
#pragma unroll
  for (int t = 0; t < NTW; ++t) {
#pragma unroll
    for (int r = 0; r < 4; ++r) {
      float p = exp2f(st[t][r] - m);
      st[t][r] = p;
      sum += p;
    }
  }
  sum += __shfl_xor(sum, 16);
  sum += __shfl_xor(sum, 32);
  float inv_s = 1.f / sum;

  // pack NORMALIZED P to bf16 pairs
  unsigned int pk0[NTW], pk1[NTW];
#pragma unroll
  for (int t = 0; t < NTW; ++t) {
    pk0[t] = (unsigned int)f2b(st[t][0] * inv_s) | ((unsigned int)f2b(st[t][1] * inv_s) << 16);
    pk1[t] = (unsigned int)f2b(st[t][2] * inv_s) | ((unsigned int)f2b(st[t][3] * inv_s) << 16);
  }

  // redistribute into A-fragments via shfl
  short8 af[7];
  int srcA = lq + (g & 1) * 32;
  int srcB = srcA + 16;
  bool hiT = (g >= 2);
#pragma unroll
  for (int e = 0; e < 7; ++e) {
    unsigned int aA0 = __shfl(pk0[2 * e], srcA);
    unsigned int aA1 = __shfl(pk1[2 * e], srcA);
    unsigned int aB0 = __shfl(pk0[2 * e], srcB);
    unsigned int aB1 = __shfl(pk1[2 * e], srcB);
    unsigned int dw0, dw1, dw2, dw3;
    if (e < 6) {
      unsigned int bA0 = __shfl(pk0[2 * e + 1], srcA);
      unsigned int bA1 = __shfl(pk1[2 * e + 1], srcA);
      unsigned int bB0 = __shfl(pk0[2 * e + 1], srcB);
      unsigned int bB1 = __shfl(pk1[2 * e + 1], srcB);
      dw0 = hiT ? bA0 : aA0; dw1 = hiT ? bA1 : aA1;
      dw2 = hiT ? bB0 : aB0; dw3 = hiT ? bB1 : aB1;
    } else {
      dw0 = hiT ? 0u : aA0; dw1 = hiT ? 0u : aA1;
      dw2 = hiT ? 0u : aB0; dw3 = hiT ? 0u : aB1;
    }
    union { unsigned int u[4]; short8 s; } t2;
    t2.u[0] = dw0; t2.u[1] = dw1; t2.u[2] = dw2; t2.u[3] = dw3;
    af[e] = t2.s;
  }

  // store P fragments (coalesced 16B/lane)
  size_t pfb = ((((size_t)h * (Tn / QBLK) + blockIdx.x) * 4 + wave) * 7) * 512 + (size_t)lane * 8;
#pragma unroll
  for (int e = 0; e < 7; ++e)
    *(short8*)(pfrag + pfb + (size_t)e * 512) = af[e];

  // PV via tr_read
  f32x4 oacc[4];
#pragma unroll
  for (int dt = 0; dt < 4; ++dt) oacc[dt] = (f32x4){0.f, 0.f, 0.f, 0.f};
  pv_tr(Vt, af, wave, lane, oacc);

  // epilogue: row = 4g+r within wave's 16 queries, col = 16dt+lq (already normalized)
#pragma unroll
  for (int dt = 0; dt < 4; ++dt)
#pragma unroll
    for (int r = 0; r < 4; ++r) {
      int i = i0 + 16 * wave + 4 * g + r;
      pv1out[headoff + (size_t)i * DHn + dt * 16 + lq] = f2b(oacc[dt][r]);
    }
}

// ---------------- pass B: pv2 = P @ pv1 (P from stored frags); combine -> y[T][C] ----------------
__global__ __launch_bounds__(256) void k_attn_b(const unsigned short* __restrict__ pv1,
                                                const unsigned short* __restrict__ v0,
                                                const unsigned short* __restrict__ pfrag,
                                                unsigned short* __restrict__ yout,
                                                const float* __restrict__ dt_logit_p) {
  __shared__ unsigned short Vt[TJ * DHn];   // subtiled pv1 tile
  int tid = threadIdx.x, lane = tid & 63, wave = tid >> 6;
  int lq = lane & 15, g = lane >> 4;
  int i0 = blockIdx.x * QBLK, h = blockIdx.y;
  int jt0 = i0 - BAND;
  const size_t headoff = (size_t)h * Tn * DHn;

  stage_subtiled(pv1 + headoff, jt0, Vt, tid, wave);

  // load P fragments
  short8 af[7];
  size_t pfb = ((((size_t)h * (Tn / QBLK) + blockIdx.x) * 4 + wave) * 7) * 512 + (size_t)lane * 8;
#pragma unroll
  for (int e = 0; e < 7; ++e)
    af[e] = *(const short8*)(pfrag + pfb + (size_t)e * 512);
  __syncthreads();

  f32x4 oacc[4];
#pragma unroll
  for (int dt = 0; dt < 4; ++dt) oacc[dt] = (f32x4){0.f, 0.f, 0.f, 0.f};
  pv_tr(Vt, af, wave, lane, oacc);

  float dtv = 1.f / (1.f + __expf(-*dt_logit_p));
  float a1 = dtv, a2 = 0.5f * dtv * dtv;
  float inv3 = 1.f / (1.f + a1 + a2);
  float w0 = inv3, w1 = a1 * inv3, w2 = a2 * inv3;

#pragma unroll
  for (int dt = 0; dt < 4; ++dt)
#pragma unroll
    for (int r = 0; r < 4; ++r) {
      int i = i0 + 16 * wave + 4 * g + r;
      // pv1[i][d] from the staged subtiled tile (row 192 + i-i0)
      int j = 192 + 16 * wave + 4 * g + r;
      unsigned boff = (unsigned)((j >> 2) * 512 + dt * 128 + (j & 3) * 32 + lq * 2);
      float p1 = b2f(*(const unsigned short*)((const char*)Vt + boff));
      float vv = b2f(v0[headoff + (size_t)i * DHn + dt * 16 + lq]);
      float yv = w0 * vv + w1 * p1 + w2 * oacc[dt][r];
      yout[(size_t)i * Cn + h * DHn + dt * 16 + lq] = f2b(yv);
    }
}

extern "C" void kernel_launch(void* const* d_in, const int* in_sizes, int n_in,
                              void* d_out, int out_size, void* d_ws, size_t ws_size,
                              hipStream_t stream) {
  (void)in_sizes; (void)n_in; (void)out_size; (void)ws_size;
  const float* x     = (const float*)d_in[0];
  const float* cosT  = (const float*)d_in[1];
  const float* sinT  = (const float*)d_in[2];
  const float* Wqkv  = (const float*)d_in[3];
  const float* Wproj = (const float*)d_in[4];
  const float* dtl   = (const float*)d_in[5];
  const float* kap   = (const float*)d_in[6];
  const float* xiu   = (const float*)d_in[7];
  float* out = (float*)d_out;
  char* ws = (char*)d_ws;
  size_t off = 0;
  auto alloc = [&](size_t bytes) { char* p = ws + off; off += (bytes + 255) & ~(size_t)255; return p; };
  unsigned short* x_bf   = (unsigned short*)alloc((size_t)Tn * Cn * 2);
  unsigned short* WqkvT  = (unsigned short*)alloc((size_t)3 * Cn * Cn * 2);
  unsigned short* WprojT = (unsigned short*)alloc((size_t)Cn * Cn * 2);
  unsigned short* q_r    = (unsigned short*)alloc((size_t)Hn * Tn * DHn * 2);
  unsigned short* k_r    = (unsigned short*)alloc((size_t)Hn * Tn * DHn * 2);
  unsigned short* v_s    = (unsigned short*)alloc((size_t)Hn * Tn * DHn * 2);
  unsigned short* pv1    = (unsigned short*)alloc((size_t)Hn * Tn * DHn * 2);
  unsigned short* y_bf   = (unsigned short*)alloc((size_t)Tn * Cn * 2);
  unsigned short* pfrag  = (unsigned short*)alloc((size_t)Hn * (Tn / QBLK) * 4 * 7 * 512 * 2);

  k_prep<<<2816, 256, 0, stream>>>(x, x_bf, Wqkv, WqkvT, Wproj, WprojT);
  k_gemm_bt<2><<<dim3(3 * Cn / 128, Tn / 128), 256, 0, stream>>>(
      x_bf, WqkvT, nullptr, Tn, 3 * Cn, Cn, cosT, sinT, q_r, k_r, v_s);
  k_attn_a<<<dim3(Tn / QBLK, Hn), 256, 0, stream>>>(q_r, k_r, v_s, pv1, pfrag, kap, xiu);
  k_attn_b<<<dim3(Tn / QBLK, Hn), 256, 0, stream>>>(pv1, v_s, pfrag, y_bf, dtl);
  k_gemm_bt<1><<<dim3(Cn / 128, Tn / 128), 256, 0, stream>>>(
      y_bf, WprojT, out, Tn, Cn, Cn, nullptr, nullptr, nullptr, nullptr, nullptr);
}

// Round 5
// 106.193 us; speedup vs baseline: 1.0448x; 1.0448x over previous
//
#include <hip/hip_runtime.h>
#include <hip/hip_bf16.h>

#define Tn 4096
#define Cn 768
#define Hn 12
#define DHn 64
#define BAND 192
#define QBLK 64
#define TJ 256        // BAND + QBLK staged keys per block
#define NTW 13        // 16-key tiles per wave (band window)

typedef __attribute__((ext_vector_type(8))) short short8;
typedef __attribute__((ext_vector_type(4))) short short4v;
typedef __attribute__((ext_vector_type(4))) float f32x4;

__device__ __forceinline__ float b2f(unsigned short u) {
  union { unsigned int i; float f; } z; z.i = ((unsigned int)u) << 16; return z.f;
}
__device__ __forceinline__ unsigned short f2b(float f) {
  union { float f; unsigned int i; } z; z.f = f;
  unsigned int r = z.i + 0x7FFFu + ((z.i >> 16) & 1u);
  return (unsigned short)(r >> 16);
}

// ---------------- prep: f32->bf16 convert + both weight transposes, one kernel ----------------
__global__ __launch_bounds__(256) void k_prep(const float* __restrict__ x,
                                              unsigned short* __restrict__ x_bf,
                                              const float* __restrict__ Wqkv,
                                              unsigned short* __restrict__ WqkvT,
                                              const float* __restrict__ Wproj,
                                              unsigned short* __restrict__ WprojT) {
  __shared__ float tile[32][33];
  int b = blockIdx.x, tid = threadIdx.x;
  if (b < 512) {
    int n4 = Tn * Cn / 4;
    for (int i = b * 256 + tid; i < n4; i += 512 * 256) {
      float4 v = ((const float4*)x)[i];
      short4v o;
      o.x = (short)f2b(v.x); o.y = (short)f2b(v.y);
      o.z = (short)f2b(v.z); o.w = (short)f2b(v.w);
      ((short4v*)x_bf)[i] = o;
    }
    return;
  }
  const float* W; unsigned short* WT; int N, r;
  if (b < 2240) { r = b - 512; W = Wqkv; WT = WqkvT; N = 3 * Cn; }
  else          { r = b - 2240; W = Wproj; WT = WprojT; N = Cn; }
  int nb = N / 32;
  int n0 = (r % nb) * 32, k0 = (r / nb) * 32;
  int tx = tid & 31, ty = tid >> 5;   // 32 x 8
  for (int rr = ty; rr < 32; rr += 8) tile[rr][tx] = W[(size_t)(k0 + rr) * N + n0 + tx];
  __syncthreads();
  for (int rr = ty; rr < 32; rr += 8) WT[(size_t)(n0 + rr) * Cn + k0 + tx] = f2b(tile[tx][rr]);
}

// ---------------- bf16 MFMA GEMM, 2-phase double-buffered, BK=64, swizzled LDS ----------------
// C[M,N] = A[M,K] * BT[N,K]^T.  EPI==1: f32 out. EPI==2: fused RoPE+split epilogue.
template<int EPI>
__global__ __launch_bounds__(256) void k_gemm_bt(const unsigned short* __restrict__ A,
                                                 const unsigned short* __restrict__ BT,
                                                 void* __restrict__ Cout,
                                                 int M, int N, int K,
                                                 const float* __restrict__ cosT,
                                                 const float* __restrict__ sinT,
                                                 unsigned short* __restrict__ qout,
                                                 unsigned short* __restrict__ kout,
                                                 unsigned short* __restrict__ vout) {
  __shared__ unsigned short As[2][128 * 64];   // [row][8 slots of 8 ushort], slot XOR-swizzled
  __shared__ unsigned short Bs[2][128 * 64];
  int tid = threadIdx.x, lane = tid & 63, wave = tid >> 6;
  int lq = lane & 15, g = lane >> 4;
  int wr = wave >> 1, wc = wave & 1;
  int m0 = blockIdx.y * 128, n0 = blockIdx.x * 128;
  f32x4 acc[4][4] = {};
  const unsigned short* Ab = A + (size_t)m0 * K;
  const unsigned short* Bb = BT + (size_t)n0 * K;

  // stage one 128x64 K-tile of A and B into buffer `buf`, global source pre-swizzled
  auto stage = [&](int buf, int k0) {
#pragma unroll
    for (int it = 0; it < 4; ++it) {
      int c = it * 256 + tid;                  // 16B chunk: row = c>>3, slot = c&7
      int row = c >> 3;
      int col8 = (c & 7) ^ (row & 7);          // inverse swizzle on source
      const unsigned short* ga = Ab + (size_t)row * K + k0 + col8 * 8;
      __builtin_amdgcn_global_load_lds((const __attribute__((address_space(1))) void*)ga,
                                       (__attribute__((address_space(3))) void*)(As[buf] + (it * 256 + wave * 64) * 8),
                                       16, 0, 0);
    }
#pragma unroll
    for (int it = 0; it < 4; ++it) {
      int c = it * 256 + tid;
      int row = c >> 3;
      int col8 = (c & 7) ^ (row & 7);
      const unsigned short* gb = Bb + (size_t)row * K + k0 + col8 * 8;
      __builtin_amdgcn_global_load_lds((const __attribute__((address_space(1))) void*)gb,
                                       (__attribute__((address_space(3))) void*)(Bs[buf] + (it * 256 + wave * 64) * 8),
                                       16, 0, 0);
    }
  };

  stage(0, 0);
  int NK = K >> 6;
  for (int kt = 0; kt < NK; ++kt) {
    int cur = kt & 1;
    if (kt + 1 < NK) {
      stage(cur ^ 1, (kt + 1) << 6);
      asm volatile("s_waitcnt vmcnt(8)" ::: "memory");   // wait only for tile-kt's 8 loads
    } else {
      asm volatile("s_waitcnt vmcnt(0)" ::: "memory");
    }
    __builtin_amdgcn_s_barrier();
    __builtin_amdgcn_sched_barrier(0);
#pragma unroll
    for (int kk = 0; kk < 2; ++kk) {
      short8 a[4], b[4];
#pragma unroll
      for (int m = 0; m < 4; ++m) {
        int row = wr * 64 + m * 16 + lq;
        int slot = (kk * 4 + g) ^ (row & 7);
        a[m] = *(const short8*)(As[cur] + row * 64 + slot * 8);
      }
#pragma unroll
      for (int n = 0; n < 4; ++n) {
        int row = wc * 64 + n * 16 + lq;
        int slot = (kk * 4 + g) ^ (row & 7);
        b[n] = *(const short8*)(Bs[cur] + row * 64 + slot * 8);
      }
#pragma unroll
      for (int m = 0; m < 4; ++m)
#pragma unroll
        for (int n = 0; n < 4; ++n)
          acc[m][n] = __builtin_amdgcn_mfma_f32_16x16x32_bf16(a[m], b[n], acc[m][n], 0, 0, 0);
    }
    __builtin_amdgcn_sched_barrier(0);
    __builtin_amdgcn_s_barrier();
  }

  int r0 = m0 + wr * 64 + g * 4;
  if (EPI == 1) {
    int c0 = n0 + wc * 64 + lq;
#pragma unroll
    for (int m = 0; m < 4; ++m)
#pragma unroll
      for (int n = 0; n < 4; ++n)
#pragma unroll
        for (int i = 0; i < 4; ++i)
          ((float*)Cout)[(size_t)(r0 + m * 16 + i) * N + c0 + n * 16] = acc[m][n][i];
  } else {
    // fused RoPE + split: this wave's 64 cols are exactly one head of q|k|v
    int col0 = n0 + wc * 64;
    int part = col0 / Cn;
    int h = (col0 % Cn) / DHn;
    unsigned short* dst = part == 0 ? qout : (part == 1 ? kout : vout);
    unsigned short* db = dst + (size_t)h * Tn * DHn;
#pragma unroll
    for (int m = 0; m < 4; ++m)
#pragma unroll
      for (int i = 0; i < 4; ++i) {
        int t = r0 + m * 16 + i;
#pragma unroll
        for (int n = 0; n < 4; ++n) {
          int d = n * 16 + lq;
          float val = acc[m][n][i];
          if (part < 2) {
            float cv = cosT[t * DHn + d], sv = sinT[t * DHn + d];
            float partner = acc[m][n ^ 2][i];
            val = (n < 2) ? fmaf(-partner, sv, val * cv) : fmaf(partner, sv, val * cv);
          }
          db[(size_t)t * DHn + d] = f2b(val);
        }
      }
  }
}

// ---- stage a 256x64 bf16 tile into LDS in 4x16-subtiled layout via global_load_lds ----
// LDS layout: addr(j,d) = (j>>2)*512 + (d>>4)*128 + (j&3)*32 + (d&15)*2   (bytes)
__device__ __forceinline__ void stage_subtiled(const unsigned short* __restrict__ srcHead,
                                               int jt0, unsigned short* lds, int tid, int wave) {
#pragma unroll
  for (int it = 0; it < 8; ++it) {
    int c = it * 256 + tid;                       // 16B chunk index
    int j = jt0 + ((c >> 5) << 2) + ((c & 7) >> 1);
    j = j < 0 ? 0 : j;
    int d0 = (((c >> 3) & 3) << 4) + ((c & 1) << 3);
    const unsigned short* ga = srcHead + (size_t)j * DHn + d0;
    __builtin_amdgcn_global_load_lds((const __attribute__((address_space(1))) void*)ga,
                                     (__attribute__((address_space(3))) void*)(lds + (it * 4 + wave) * 512),
                                     16, 0, 0);
  }
}

// ---- PV: 7 A-frags (P) x subtiled-V tile -> oacc[4] via ds_read_b64_tr_b16 ----
__device__ __forceinline__ void pv_tr(const unsigned short* Vt, const short8* af,
                                      int wave, int lane, f32x4* oacc) {
  int lq = lane & 15, g = lane >> 4;
  unsigned base = (unsigned)(size_t)(const __attribute__((address_space(3))) unsigned short*)Vt;
  unsigned pl = base + lq * 8;
#pragma unroll
  for (int e = 0; e < 7; ++e) {
    int kl = 16 * wave + 32 * e + 8 * g;
    if (kl > TJ - 8) kl = TJ - 8;          // those lanes carry p==0
    unsigned pe = pl + kl * 128;
    unsigned long long rr[8];
#pragma unroll
    for (int dt = 0; dt < 4; ++dt) {
      asm volatile("ds_read_b64_tr_b16 %0, %1" : "=v"(rr[2 * dt]) : "v"(pe + dt * 128));
      asm volatile("ds_read_b64_tr_b16 %0, %1" : "=v"(rr[2 * dt + 1]) : "v"(pe + dt * 128 + 512));
    }
    asm volatile("s_waitcnt lgkmcnt(0)");
    __builtin_amdgcn_sched_barrier(0);
#pragma unroll
    for (int dt = 0; dt < 4; ++dt) {
      union { unsigned long long u[2]; short8 s; } vb;
      vb.u[0] = rr[2 * dt]; vb.u[1] = rr[2 * dt + 1];
      oacc[dt] = __builtin_amdgcn_mfma_f32_16x16x32_bf16(af[e], vb.s, oacc[dt], 0, 0, 0);
    }
  }
}

// ---------------- pass A: QK^T + softmax; write pv1 and normalized P fragments ----------------
__global__ __launch_bounds__(256) void k_attn_a(const unsigned short* __restrict__ qr,
                                                const unsigned short* __restrict__ kr,
                                                const unsigned short* __restrict__ vin,
                                                unsigned short* __restrict__ pv1out,
                                                unsigned short* __restrict__ pfrag,
                                                const float* __restrict__ kap_p,
                                                const float* __restrict__ xi_p) {
  __shared__ unsigned short Ks[TJ * DHn];   // row-major, 16B-unit XOR swizzle per row
  __shared__ unsigned short Vt[TJ * DHn];   // 4x16 subtiled for tr_read
  int tid = threadIdx.x, lane = tid & 63, wave = tid >> 6;
  int lq = lane & 15, g = lane >> 4;
  int i0 = blockIdx.x * QBLK, h = blockIdx.y;
  int jt0 = i0 - BAND;
  const size_t headoff = (size_t)h * Tn * DHn;

  // stage K (swizzled rows, pre-swizzled global source)
  const unsigned short* krh = kr + headoff;
#pragma unroll
  for (int it = 0; it < 8; ++it) {
    int u = it * 256 + tid;
    int row = u >> 3, c8 = u & 7;
    int j = jt0 + row; j = j < 0 ? 0 : j;
    const unsigned short* ga = krh + (size_t)j * DHn + ((c8 ^ (row & 7)) << 3);
    __builtin_amdgcn_global_load_lds((const __attribute__((address_space(1))) void*)ga,
                                     (__attribute__((address_space(3))) void*)((char*)Ks + (size_t)(it * 256 + wave * 64) * 16),
                                     16, 0, 0);
  }
  // stage V subtiled
  stage_subtiled(vin + headoff, jt0, Vt, tid, wave);

  // Q fragments from global
  const unsigned short* qrh = qr + headoff;
  int q0 = i0 + wave * 16;
  short8 qf0 = *(const short8*)(qrh + (size_t)(q0 + lq) * DHn + g * 8);
  short8 qf1 = *(const short8*)(qrh + (size_t)(q0 + lq) * DHn + 32 + g * 8);
  __syncthreads();

  // S^T = K . Q^T over this wave's 13 key tiles
  f32x4 st[NTW];
#pragma unroll
  for (int t = 0; t < NTW; ++t) st[t] = (f32x4){0.f, 0.f, 0.f, 0.f};
#pragma unroll
  for (int t = 0; t < NTW; ++t) {
    int row = (wave + t) * 16 + lq;
    const char* kb = (const char*)Ks + row * 128;
    int sw = row & 7;
    short8 ka0 = *(const short8*)(kb + ((g ^ sw) << 4));
    short8 ka1 = *(const short8*)(kb + (((4 + g) ^ sw) << 4));
    st[t] = __builtin_amdgcn_mfma_f32_16x16x32_bf16(ka0, qf0, st[t], 0, 0, 0);
    st[t] = __builtin_amdgcn_mfma_f32_16x16x32_bf16(ka1, qf1, st[t], 0, 0, 0);
  }

  // softmax (log2 domain), lane-local + 2 shfl_xor
  float kap = log1pf(__expf(*kap_p));
  float xi  = log1pf(__expf(*xi_p));
  const float LOG2E = 1.4426950408889634f;
  float sc = 0.125f * LOG2E;
  float c2 = kap / (xi * xi) * LOG2E;
  float db0 = (float)(lq + BAND - 4 * g);
  float jb0 = (float)(jt0 + 16 * wave + 4 * g);
  float m = -3.0e38f;
#pragma unroll
  for (int t = 0; t < NTW; ++t) {
#pragma unroll
    for (int r = 0; r < 4; ++r) {
      float off = (float)(16 * t + r);
      float dist = db0 - off;
      float jv = jb0 + off;
      float l2 = fmaf(dist * dist, -c2, st[t][r] * sc);
      bool bad = (dist < 0.f) || (jv < 0.f);
      l2 = bad ? -3.0e38f : l2;
      st[t][r] = l2;
      m = fmaxf(m, l2);
    }
  }
  m = fmaxf(m, __shfl_xor(m, 16));
  m = fmaxf(m, __shfl_xor(m, 32));
  float sum = 0.f;
#pragma unroll
  for (int t = 0; t < NTW; ++t) {
#pragma unroll
    for (int r = 0; r < 4; ++r) {
      float p = exp2f(st[t][r] - m);
      st[t][r] = p;
      sum += p;
    }
  }
  sum += __shfl_xor(sum, 16);
  sum += __shfl_xor(sum, 32);
  float inv_s = 1.f / sum;

  // pack NORMALIZED P to bf16 pairs
  unsigned int pk0[NTW], pk1[NTW];
#pragma unroll
  for (int t = 0; t < NTW; ++t) {
    pk0[t] = (unsigned int)f2b(st[t][0] * inv_s) | ((unsigned int)f2b(st[t][1] * inv_s) << 16);
    pk1[t] = (unsigned int)f2b(st[t][2] * inv_s) | ((unsigned int)f2b(st[t][3] * inv_s) << 16);
  }

  // redistribute into A-fragments via shfl
  short8 af[7];
  int srcA = lq + (g & 1) * 32;
  int srcB = srcA + 16;
  bool hiT = (g >= 2);
#pragma unroll
  for (int e = 0; e < 7; ++e) {
    unsigned int aA0 = __shfl(pk0[2 * e], srcA);
    unsigned int aA1 = __shfl(pk1[2 * e], srcA);
    unsigned int aB0 = __shfl(pk0[2 * e], srcB);
    unsigned int aB1 = __shfl(pk1[2 * e], srcB);
    unsigned int dw0, dw1, dw2, dw3;
    if (e < 6) {
      unsigned int bA0 = __shfl(pk0[2 * e + 1], srcA);
      unsigned int bA1 = __shfl(pk1[2 * e + 1], srcA);
      unsigned int bB0 = __shfl(pk0[2 * e + 1], srcB);
      unsigned int bB1 = __shfl(pk1[2 * e + 1], srcB);
      dw0 = hiT ? bA0 : aA0; dw1 = hiT ? bA1 : aA1;
      dw2 = hiT ? bB0 : aB0; dw3 = hiT ? bB1 : aB1;
    } else {
      dw0 = hiT ? 0u : aA0; dw1 = hiT ? 0u : aA1;
      dw2 = hiT ? 0u : aB0; dw3 = hiT ? 0u : aB1;
    }
    union { unsigned int u[4]; short8 s; } t2;
    t2.u[0] = dw0; t2.u[1] = dw1; t2.u[2] = dw2; t2.u[3] = dw3;
    af[e] = t2.s;
  }

  // store P fragments (coalesced 16B/lane)
  size_t pfb = ((((size_t)h * (Tn / QBLK) + blockIdx.x) * 4 + wave) * 7) * 512 + (size_t)lane * 8;
#pragma unroll
  for (int e = 0; e < 7; ++e)
    *(short8*)(pfrag + pfb + (size_t)e * 512) = af[e];

  // PV via tr_read
  f32x4 oacc[4];
#pragma unroll
  for (int dt = 0; dt < 4; ++dt) oacc[dt] = (f32x4){0.f, 0.f, 0.f, 0.f};
  pv_tr(Vt, af, wave, lane, oacc);

  // epilogue: row = 4g+r within wave's 16 queries, col = 16dt+lq (already normalized)
#pragma unroll
  for (int dt = 0; dt < 4; ++dt)
#pragma unroll
    for (int r = 0; r < 4; ++r) {
      int i = i0 + 16 * wave + 4 * g + r;
      pv1out[headoff + (size_t)i * DHn + dt * 16 + lq] = f2b(oacc[dt][r]);
    }
}

// ---------------- pass B: pv2 = P @ pv1 (P from stored frags); combine -> y[T][C] ----------------
__global__ __launch_bounds__(256) void k_attn_b(const unsigned short* __restrict__ pv1,
                                                const unsigned short* __restrict__ v0,
                                                const unsigned short* __restrict__ pfrag,
                                                unsigned short* __restrict__ yout,
                                                const float* __restrict__ dt_logit_p) {
  __shared__ unsigned short Vt[TJ * DHn];   // subtiled pv1 tile
  int tid = threadIdx.x, lane = tid & 63, wave = tid >> 6;
  int lq = lane & 15, g = lane >> 4;
  int i0 = blockIdx.x * QBLK, h = blockIdx.y;
  int jt0 = i0 - BAND;
  const size_t headoff = (size_t)h * Tn * DHn;

  stage_subtiled(pv1 + headoff, jt0, Vt, tid, wave);

  // load P fragments
  short8 af[7];
  size_t pfb = ((((size_t)h * (Tn / QBLK) + blockIdx.x) * 4 + wave) * 7) * 512 + (size_t)lane * 8;
#pragma unroll
  for (int e = 0; e < 7; ++e)
    af[e] = *(const short8*)(pfrag + pfb + (size_t)e * 512);
  __syncthreads();

  f32x4 oacc[4];
#pragma unroll
  for (int dt = 0; dt < 4; ++dt) oacc[dt] = (f32x4){0.f, 0.f, 0.f, 0.f};
  pv_tr(Vt, af, wave, lane, oacc);

  float dtv = 1.f / (1.f + __expf(-*dt_logit_p));
  float a1 = dtv, a2 = 0.5f * dtv * dtv;
  float inv3 = 1.f / (1.f + a1 + a2);
  float w0 = inv3, w1 = a1 * inv3, w2 = a2 * inv3;

#pragma unroll
  for (int dt = 0; dt < 4; ++dt)
#pragma unroll
    for (int r = 0; r < 4; ++r) {
      int i = i0 + 16 * wave + 4 * g + r;
      // pv1[i][d] from the staged subtiled tile (row 192 + i-i0)
      int j = 192 + 16 * wave + 4 * g + r;
      unsigned boff = (unsigned)((j >> 2) * 512 + dt * 128 + (j & 3) * 32 + lq * 2);
      float p1 = b2f(*(const unsigned short*)((const char*)Vt + boff));
      float vv = b2f(v0[headoff + (size_t)i * DHn + dt * 16 + lq]);
      float yv = w0 * vv + w1 * p1 + w2 * oacc[dt][r];
      yout[(size_t)i * Cn + h * DHn + dt * 16 + lq] = f2b(yv);
    }
}

extern "C" void kernel_launch(void* const* d_in, const int* in_sizes, int n_in,
                              void* d_out, int out_size, void* d_ws, size_t ws_size,
                              hipStream_t stream) {
  (void)in_sizes; (void)n_in; (void)out_size; (void)ws_size;
  const float* x     = (const float*)d_in[0];
  const float* cosT  = (const float*)d_in[1];
  const float* sinT  = (const float*)d_in[2];
  const float* Wqkv  = (const float*)d_in[3];
  const float* Wproj = (const float*)d_in[4];
  const float* dtl   = (const float*)d_in[5];
  const float* kap   = (const float*)d_in[6];
  const float* xiu   = (const float*)d_in[7];
  float* out = (float*)d_out;
  char* ws = (char*)d_ws;
  size_t off = 0;
  auto alloc = [&](size_t bytes) { char* p = ws + off; off += (bytes + 255) & ~(size_t)255; return p; };
  unsigned short* x_bf   = (unsigned short*)alloc((size_t)Tn * Cn * 2);
  unsigned short* WqkvT  = (unsigned short*)alloc((size_t)3 * Cn * Cn * 2);
  unsigned short* WprojT = (unsigned short*)alloc((size_t)Cn * Cn * 2);
  unsigned short* q_r    = (unsigned short*)alloc((size_t)Hn * Tn * DHn * 2);
  unsigned short* k_r    = (unsigned short*)alloc((size_t)Hn * Tn * DHn * 2);
  unsigned short* v_s    = (unsigned short*)alloc((size_t)Hn * Tn * DHn * 2);
  unsigned short* pv1    = (unsigned short*)alloc((size_t)Hn * Tn * DHn * 2);
  unsigned short* y_bf   = (unsigned short*)alloc((size_t)Tn * Cn * 2);
  unsigned short* pfrag  = (unsigned short*)alloc((size_t)Hn * (Tn / QBLK) * 4 * 7 * 512 * 2);

  k_prep<<<2816, 256, 0, stream>>>(x, x_bf, Wqkv, WqkvT, Wproj, WprojT);
  k_gemm_bt<2><<<dim3(3 * Cn / 128, Tn / 128), 256, 0, stream>>>(
      x_bf, WqkvT, nullptr, Tn, 3 * Cn, Cn, cosT, sinT, q_r, k_r, v_s);
  k_attn_a<<<dim3(Tn / QBLK, Hn), 256, 0, stream>>>(q_r, k_r, v_s, pv1, pfrag, kap, xiu);
  k_attn_b<<<dim3(Tn / QBLK, Hn), 256, 0, stream>>>(pv1, v_s, pfrag, y_bf, dtl);
  k_gemm_bt<1><<<dim3(Cn / 128, Tn / 128), 256, 0, stream>>>(
      y_bf, WprojT, out, Tn, Cn, Cn, nullptr, nullptr, nullptr, nullptr, nullptr);
}

// Round 6
// 100.658 us; speedup vs baseline: 1.1022x; 1.0550x over previous
//
#include <hip/hip_runtime.h>
#include <hip/hip_bf16.h>

#define Tn 4096
#define Cn 768
#define Hn 12
#define DHn 64
#define BAND 192
#define QBLK 64
#define TJ 256        // BAND + QBLK staged keys per block
#define NTW 13        // 16-key tiles per wave (band window)

typedef __attribute__((ext_vector_type(8))) short short8;
typedef __attribute__((ext_vector_type(4))) short short4v;
typedef __attribute__((ext_vector_type(4))) float f32x4;

__device__ __forceinline__ float b2f(unsigned short u) {
  union { unsigned int i; float f; } z; z.i = ((unsigned int)u) << 16; return z.f;
}
__device__ __forceinline__ unsigned short f2b(float f) {
  union { float f; unsigned int i; } z; z.f = f;
  unsigned int r = z.i + 0x7FFFu + ((z.i >> 16) & 1u);
  return (unsigned short)(r >> 16);
}

// ---------------- prep: f32->bf16 convert + both weight transposes, one kernel ----------------
__global__ __launch_bounds__(256) void k_prep(const float* __restrict__ x,
                                              unsigned short* __restrict__ x_bf,
                                              const float* __restrict__ Wqkv,
                                              unsigned short* __restrict__ WqkvT,
                                              const float* __restrict__ Wproj,
                                              unsigned short* __restrict__ WprojT) {
  __shared__ float tile[32][33];
  int b = blockIdx.x, tid = threadIdx.x;
  if (b < 512) {
    int n4 = Tn * Cn / 4;
    for (int i = b * 256 + tid; i < n4; i += 512 * 256) {
      float4 v = ((const float4*)x)[i];
      short4v o;
      o.x = (short)f2b(v.x); o.y = (short)f2b(v.y);
      o.z = (short)f2b(v.z); o.w = (short)f2b(v.w);
      ((short4v*)x_bf)[i] = o;
    }
    return;
  }
  const float* W; unsigned short* WT; int N, r;
  if (b < 2240) { r = b - 512; W = Wqkv; WT = WqkvT; N = 3 * Cn; }
  else          { r = b - 2240; W = Wproj; WT = WprojT; N = Cn; }
  int nb = N / 32;
  int n0 = (r % nb) * 32, k0 = (r / nb) * 32;
  int tx = tid & 31, ty = tid >> 5;   // 32 x 8
  for (int rr = ty; rr < 32; rr += 8) tile[rr][tx] = W[(size_t)(k0 + rr) * N + n0 + tx];
  __syncthreads();
  for (int rr = ty; rr < 32; rr += 8) WT[(size_t)(n0 + rr) * Cn + k0 + tx] = f2b(tile[tx][rr]);
}

// ---------------- bf16 MFMA GEMM, 4-deep pipelined, BK=32, 8 waves, XCD-swizzled ----------------
// C[M,N] = A[M,K] * BT[N,K]^T.  EPI==1: f32 out. EPI==2: fused RoPE+split epilogue.
template<int EPI>
__global__ __launch_bounds__(512, 4) void k_gemm_bt(const unsigned short* __restrict__ A,
                                                    const unsigned short* __restrict__ BT,
                                                    void* __restrict__ Cout,
                                                    int M, int N, int K,
                                                    const float* __restrict__ cosT,
                                                    const float* __restrict__ sinT,
                                                    unsigned short* __restrict__ qout,
                                                    unsigned short* __restrict__ kout,
                                                    unsigned short* __restrict__ vout) {
  __shared__ unsigned short As[4][128 * 32];   // 4-deep; [row][4 slots of 16B], slot XOR-swizzled
  __shared__ unsigned short Bs[4][128 * 32];
  int tid = threadIdx.x, lane = tid & 63, wave = tid >> 6;
  int lq = lane & 15, g = (lane >> 4) & 3;
  int wr = wave >> 1, wc = wave & 1;              // 8 waves: 4 row-groups x 2 col-halves

  // bijective XCD-aware swizzle (nwg % 8 == 0 for both grids)
  int nx = gridDim.x;
  int nwg = nx * gridDim.y;
  int lid = blockIdx.y * nx + blockIdx.x;
  int swz = (lid & 7) * (nwg >> 3) + (lid >> 3);
  int bx = swz % nx, by = swz / nx;
  int m0 = by * 128, n0 = bx * 128;

  const unsigned short* Ab = A + (size_t)m0 * K;
  const unsigned short* Bb = BT + (size_t)n0 * K;

  // per-thread staging coords: chunk = tid; row = tid>>2; swizzled source slot
  int srow = tid >> 2;
  int scol = (tid & 3) ^ (srow & 3) ^ ((srow >> 2) & 3);
  const unsigned short* gA = Ab + (size_t)srow * K + scol * 8;
  const unsigned short* gB = Bb + (size_t)srow * K + scol * 8;

  auto stage = [&](int buf, int kt) {
    int k0 = kt << 5;
    __builtin_amdgcn_global_load_lds((const __attribute__((address_space(1))) void*)(gA + k0),
                                     (__attribute__((address_space(3))) void*)(As[buf] + wave * 512),
                                     16, 0, 0);
    __builtin_amdgcn_global_load_lds((const __attribute__((address_space(1))) void*)(gB + k0),
                                     (__attribute__((address_space(3))) void*)(Bs[buf] + wave * 512),
                                     16, 0, 0);
  };

  f32x4 acc[2][4] = {};
  int NK = K >> 5;                 // 24
  stage(0, 0); stage(1, 1); stage(2, 2);
  for (int kt = 0; kt < NK; ++kt) {
    if (kt + 3 < NK) stage((kt + 3) & 3, kt + 3);
    int rem = NK - 1 - kt;
    if (rem >= 3)      asm volatile("s_waitcnt vmcnt(6)" ::: "memory");
    else if (rem == 2) asm volatile("s_waitcnt vmcnt(4)" ::: "memory");
    else if (rem == 1) asm volatile("s_waitcnt vmcnt(2)" ::: "memory");
    else               asm volatile("s_waitcnt vmcnt(0)" ::: "memory");
    __builtin_amdgcn_s_barrier();
    const unsigned short* Ac = As[kt & 3];
    const unsigned short* Bc = Bs[kt & 3];
    short8 a[2], b[4];
#pragma unroll
    for (int m = 0; m < 2; ++m) {
      int row = wr * 32 + m * 16 + lq;
      int s = g ^ (row & 3) ^ ((row >> 2) & 3);
      a[m] = *(const short8*)(Ac + row * 32 + s * 8);
    }
#pragma unroll
    for (int n = 0; n < 4; ++n) {
      int row = wc * 64 + n * 16 + lq;
      int s = g ^ (row & 3) ^ ((row >> 2) & 3);
      b[n] = *(const short8*)(Bc + row * 32 + s * 8);
    }
#pragma unroll
    for (int m = 0; m < 2; ++m)
#pragma unroll
      for (int n = 0; n < 4; ++n)
        acc[m][n] = __builtin_amdgcn_mfma_f32_16x16x32_bf16(a[m], b[n], acc[m][n], 0, 0, 0);
    asm volatile("s_waitcnt lgkmcnt(0)" ::: "memory");
    __builtin_amdgcn_s_barrier();
  }

  int r0 = m0 + wr * 32 + g * 4;
  if (EPI == 1) {
    int c0 = n0 + wc * 64 + lq;
#pragma unroll
    for (int m = 0; m < 2; ++m)
#pragma unroll
      for (int n = 0; n < 4; ++n)
#pragma unroll
        for (int i = 0; i < 4; ++i)
          ((float*)Cout)[(size_t)(r0 + m * 16 + i) * N + c0 + n * 16] = acc[m][n][i];
  } else {
    // fused RoPE + split: this wave's 64 cols are exactly one head of q|k|v
    int col0 = n0 + wc * 64;
    int part = col0 / Cn;
    int h = (col0 % Cn) / DHn;
    unsigned short* dst = part == 0 ? qout : (part == 1 ? kout : vout);
    unsigned short* db = dst + (size_t)h * Tn * DHn;
#pragma unroll
    for (int m = 0; m < 2; ++m)
#pragma unroll
      for (int i = 0; i < 4; ++i) {
        int t = r0 + m * 16 + i;
#pragma unroll
        for (int n = 0; n < 4; ++n) {
          int d = n * 16 + lq;
          float val = acc[m][n][i];
          if (part < 2) {
            float cv = cosT[t * DHn + d], sv = sinT[t * DHn + d];
            float partner = acc[m][n ^ 2][i];
            val = (n < 2) ? fmaf(-partner, sv, val * cv) : fmaf(partner, sv, val * cv);
          }
          db[(size_t)t * DHn + d] = f2b(val);
        }
      }
  }
}

// ---- stage a 256x64 bf16 tile into LDS in 4x16-subtiled layout via global_load_lds ----
// LDS layout: addr(j,d) = (j>>2)*512 + (d>>4)*128 + (j&3)*32 + (d&15)*2   (bytes)
__device__ __forceinline__ void stage_subtiled(const unsigned short* __restrict__ srcHead,
                                               int jt0, unsigned short* lds, int tid, int wave) {
#pragma unroll
  for (int it = 0; it < 8; ++it) {
    int c = it * 256 + tid;                       // 16B chunk index
    int j = jt0 + ((c >> 5) << 2) + ((c & 7) >> 1);
    j = j < 0 ? 0 : j;
    int d0 = (((c >> 3) & 3) << 4) + ((c & 1) << 3);
    const unsigned short* ga = srcHead + (size_t)j * DHn + d0;
    __builtin_amdgcn_global_load_lds((const __attribute__((address_space(1))) void*)ga,
                                     (__attribute__((address_space(3))) void*)(lds + (it * 4 + wave) * 512),
                                     16, 0, 0);
  }
}

// ---- PV: 7 A-frags (P) x subtiled-V tile -> oacc[4] via ds_read_b64_tr_b16 ----
__device__ __forceinline__ void pv_tr(const unsigned short* Vt, const short8* af,
                                      int wave, int lane, f32x4* oacc) {
  int lq = lane & 15, g = lane >> 4;
  unsigned base = (unsigned)(size_t)(const __attribute__((address_space(3))) unsigned short*)Vt;
  unsigned pl = base + lq * 8;
#pragma unroll
  for (int e = 0; e < 7; ++e) {
    int kl = 16 * wave + 32 * e + 8 * g;
    if (kl > TJ - 8) kl = TJ - 8;          // those lanes carry p==0
    unsigned pe = pl + kl * 128;
    unsigned long long rr[8];
#pragma unroll
    for (int dt = 0; dt < 4; ++dt) {
      asm volatile("ds_read_b64_tr_b16 %0, %1" : "=v"(rr[2 * dt]) : "v"(pe + dt * 128));
      asm volatile("ds_read_b64_tr_b16 %0, %1" : "=v"(rr[2 * dt + 1]) : "v"(pe + dt * 128 + 512));
    }
    asm volatile("s_waitcnt lgkmcnt(0)");
    __builtin_amdgcn_sched_barrier(0);
#pragma unroll
    for (int dt = 0; dt < 4; ++dt) {
      union { unsigned long long u[2]; short8 s; } vb;
      vb.u[0] = rr[2 * dt]; vb.u[1] = rr[2 * dt + 1];
      oacc[dt] = __builtin_amdgcn_mfma_f32_16x16x32_bf16(af[e], vb.s, oacc[dt], 0, 0, 0);
    }
  }
}

// ---------------- pass A: QK^T + softmax; write pv1 and normalized P fragments ----------------
__global__ __launch_bounds__(256) void k_attn_a(const unsigned short* __restrict__ qr,
                                                const unsigned short* __restrict__ kr,
                                                const unsigned short* __restrict__ vin,
                                                unsigned short* __restrict__ pv1out,
                                                unsigned short* __restrict__ pfrag,
                                                const float* __restrict__ kap_p,
                                                const float* __restrict__ xi_p) {
  __shared__ unsigned short Ks[TJ * DHn];   // row-major, 16B-unit XOR swizzle per row
  __shared__ unsigned short Vt[TJ * DHn];   // 4x16 subtiled for tr_read
  int tid = threadIdx.x, lane = tid & 63, wave = tid >> 6;
  int lq = lane & 15, g = lane >> 4;
  int i0 = blockIdx.x * QBLK, h = blockIdx.y;
  int jt0 = i0 - BAND;
  const size_t headoff = (size_t)h * Tn * DHn;

  // stage K (swizzled rows, pre-swizzled global source)
  const unsigned short* krh = kr + headoff;
#pragma unroll
  for (int it = 0; it < 8; ++it) {
    int u = it * 256 + tid;
    int row = u >> 3, c8 = u & 7;
    int j = jt0 + row; j = j < 0 ? 0 : j;
    const unsigned short* ga = krh + (size_t)j * DHn + ((c8 ^ (row & 7)) << 3);
    __builtin_amdgcn_global_load_lds((const __attribute__((address_space(1))) void*)ga,
                                     (__attribute__((address_space(3))) void*)((char*)Ks + (size_t)(it * 256 + wave * 64) * 16),
                                     16, 0, 0);
  }
  // stage V subtiled
  stage_subtiled(vin + headoff, jt0, Vt, tid, wave);

  // Q fragments from global
  const unsigned short* qrh = qr + headoff;
  int q0 = i0 + wave * 16;
  short8 qf0 = *(const short8*)(qrh + (size_t)(q0 + lq) * DHn + g * 8);
  short8 qf1 = *(const short8*)(qrh + (size_t)(q0 + lq) * DHn + 32 + g * 8);
  __syncthreads();

  // S^T = K . Q^T over this wave's 13 key tiles
  f32x4 st[NTW];
#pragma unroll
  for (int t = 0; t < NTW; ++t) st[t] = (f32x4){0.f, 0.f, 0.f, 0.f};
#pragma unroll
  for (int t = 0; t < NTW; ++t) {
    int row = (wave + t) * 16 + lq;
    const char* kb = (const char*)Ks + row * 128;
    int sw = row & 7;
    short8 ka0 = *(const short8*)(kb + ((g ^ sw) << 4));
    short8 ka1 = *(const short8*)(kb + (((4 + g) ^ sw) << 4));
    st[t] = __builtin_amdgcn_mfma_f32_16x16x32_bf16(ka0, qf0, st[t], 0, 0, 0);
    st[t] = __builtin_amdgcn_mfma_f32_16x16x32_bf16(ka1, qf1, st[t], 0, 0, 0);
  }

  // softmax (log2 domain), lane-local + 2 shfl_xor
  float kap = log1pf(__expf(*kap_p));
  float xi  = log1pf(__expf(*xi_p));
  const float LOG2E = 1.4426950408889634f;
  float sc = 0.125f * LOG2E;
  float c2 = kap / (xi * xi) * LOG2E;
  float db0 = (float)(lq + BAND - 4 * g);
  float jb0 = (float)(jt0 + 16 * wave + 4 * g);
  float m = -3.0e38f;
#pragma unroll
  for (int t = 0; t < NTW; ++t) {
#pragma unroll
    for (int r = 0; r < 4; ++r) {
      float off = (float)(16 * t + r);
      float dist = db0 - off;
      float jv = jb0 + off;
      float l2 = fmaf(dist * dist, -c2, st[t][r] * sc);
      bool bad = (dist < 0.f) || (jv < 0.f);
      l2 = bad ? -3.0e38f : l2;
      st[t][r] = l2;
      m = fmaxf(m, l2);
    }
  }
  m = fmaxf(m, __shfl_xor(m, 16));
  m = fmaxf(m, __shfl_xor(m, 32));
  float sum = 0.f;
#pragma unroll
  for (int t = 0; t < NTW; ++t) {
#pragma unroll
    for (int r = 0; r < 4; ++r) {
      float p = exp2f(st[t][r] - m);
      st[t][r] = p;
      sum += p;
    }
  }
  sum += __shfl_xor(sum, 16);
  sum += __shfl_xor(sum, 32);
  float inv_s = 1.f / sum;

  // pack NORMALIZED P to bf16 pairs
  unsigned int pk0[NTW], pk1[NTW];
#pragma unroll
  for (int t = 0; t < NTW; ++t) {
    pk0[t] = (unsigned int)f2b(st[t][0] * inv_s) | ((unsigned int)f2b(st[t][1] * inv_s) << 16);
    pk1[t] = (unsigned int)f2b(st[t][2] * inv_s) | ((unsigned int)f2b(st[t][3] * inv_s) << 16);
  }

  // redistribute into A-fragments via shfl
  short8 af[7];
  int srcA = lq + (g & 1) * 32;
  int srcB = srcA + 16;
  bool hiT = (g >= 2);
#pragma unroll
  for (int e = 0; e < 7; ++e) {
    unsigned int aA0 = __shfl(pk0[2 * e], srcA);
    unsigned int aA1 = __shfl(pk1[2 * e], srcA);
    unsigned int aB0 = __shfl(pk0[2 * e], srcB);
    unsigned int aB1 = __shfl(pk1[2 * e], srcB);
    unsigned int dw0, dw1, dw2, dw3;
    if (e < 6) {
      unsigned int bA0 = __shfl(pk0[2 * e + 1], srcA);
      unsigned int bA1 = __shfl(pk1[2 * e + 1], srcA);
      unsigned int bB0 = __shfl(pk0[2 * e + 1], srcB);
      unsigned int bB1 = __shfl(pk1[2 * e + 1], srcB);
      dw0 = hiT ? bA0 : aA0; dw1 = hiT ? bA1 : aA1;
      dw2 = hiT ? bB0 : aB0; dw3 = hiT ? bB1 : aB1;
    } else {
      dw0 = hiT ? 0u : aA0; dw1 = hiT ? 0u : aA1;
      dw2 = hiT ? 0u : aB0; dw3 = hiT ? 0u : aB1;
    }
    union { unsigned int u[4]; short8 s; } t2;
    t2.u[0] = dw0; t2.u[1] = dw1; t2.u[2] = dw2; t2.u[3] = dw3;
    af[e] = t2.s;
  }

  // store P fragments (coalesced 16B/lane)
  size_t pfb = ((((size_t)h * (Tn / QBLK) + blockIdx.x) * 4 + wave) * 7) * 512 + (size_t)lane * 8;
#pragma unroll
  for (int e = 0; e < 7; ++e)
    *(short8*)(pfrag + pfb + (size_t)e * 512) = af[e];

  // PV via tr_read
  f32x4 oacc[4];
#pragma unroll
  for (int dt = 0; dt < 4; ++dt) oacc[dt] = (f32x4){0.f, 0.f, 0.f, 0.f};
  pv_tr(Vt, af, wave, lane, oacc);

  // epilogue: row = 4g+r within wave's 16 queries, col = 16dt+lq (already normalized)
#pragma unroll
  for (int dt = 0; dt < 4; ++dt)
#pragma unroll
    for (int r = 0; r < 4; ++r) {
      int i = i0 + 16 * wave + 4 * g + r;
      pv1out[headoff + (size_t)i * DHn + dt * 16 + lq] = f2b(oacc[dt][r]);
    }
}

// ---------------- pass B: pv2 = P @ pv1 (P from stored frags); combine -> y[T][C] ----------------
__global__ __launch_bounds__(256) void k_attn_b(const unsigned short* __restrict__ pv1,
                                                const unsigned short* __restrict__ v0,
                                                const unsigned short* __restrict__ pfrag,
                                                unsigned short* __restrict__ yout,
                                                const float* __restrict__ dt_logit_p) {
  __shared__ unsigned short Vt[TJ * DHn];   // subtiled pv1 tile
  int tid = threadIdx.x, lane = tid & 63, wave = tid >> 6;
  int lq = lane & 15, g = lane >> 4;
  int i0 = blockIdx.x * QBLK, h = blockIdx.y;
  int jt0 = i0 - BAND;
  const size_t headoff = (size_t)h * Tn * DHn;

  stage_subtiled(pv1 + headoff, jt0, Vt, tid, wave);

  // load P fragments
  short8 af[7];
  size_t pfb = ((((size_t)h * (Tn / QBLK) + blockIdx.x) * 4 + wave) * 7) * 512 + (size_t)lane * 8;
#pragma unroll
  for (int e = 0; e < 7; ++e)
    af[e] = *(const short8*)(pfrag + pfb + (size_t)e * 512);
  __syncthreads();

  f32x4 oacc[4];
#pragma unroll
  for (int dt = 0; dt < 4; ++dt) oacc[dt] = (f32x4){0.f, 0.f, 0.f, 0.f};
  pv_tr(Vt, af, wave, lane, oacc);

  float dtv = 1.f / (1.f + __expf(-*dt_logit_p));
  float a1 = dtv, a2 = 0.5f * dtv * dtv;
  float inv3 = 1.f / (1.f + a1 + a2);
  float w0 = inv3, w1 = a1 * inv3, w2 = a2 * inv3;

#pragma unroll
  for (int dt = 0; dt < 4; ++dt)
#pragma unroll
    for (int r = 0; r < 4; ++r) {
      int i = i0 + 16 * wave + 4 * g + r;
      // pv1[i][d] from the staged subtiled tile (row 192 + i-i0)
      int j = 192 + 16 * wave + 4 * g + r;
      unsigned boff = (unsigned)((j >> 2) * 512 + dt * 128 + (j & 3) * 32 + lq * 2);
      float p1 = b2f(*(const unsigned short*)((const char*)Vt + boff));
      float vv = b2f(v0[headoff + (size_t)i * DHn + dt * 16 + lq]);
      float yv = w0 * vv + w1 * p1 + w2 * oacc[dt][r];
      yout[(size_t)i * Cn + h * DHn + dt * 16 + lq] = f2b(yv);
    }
}

extern "C" void kernel_launch(void* const* d_in, const int* in_sizes, int n_in,
                              void* d_out, int out_size, void* d_ws, size_t ws_size,
                              hipStream_t stream) {
  (void)in_sizes; (void)n_in; (void)out_size; (void)ws_size;
  const float* x     = (const float*)d_in[0];
  const float* cosT  = (const float*)d_in[1];
  const float* sinT  = (const float*)d_in[2];
  const float* Wqkv  = (const float*)d_in[3];
  const float* Wproj = (const float*)d_in[4];
  const float* dtl   = (const float*)d_in[5];
  const float* kap   = (const float*)d_in[6];
  const float* xiu   = (const float*)d_in[7];
  float* out = (float*)d_out;
  char* ws = (char*)d_ws;
  size_t off = 0;
  auto alloc = [&](size_t bytes) { char* p = ws + off; off += (bytes + 255) & ~(size_t)255; return p; };
  unsigned short* x_bf   = (unsigned short*)alloc((size_t)Tn * Cn * 2);
  unsigned short* WqkvT  = (unsigned short*)alloc((size_t)3 * Cn * Cn * 2);
  unsigned short* WprojT = (unsigned short*)alloc((size_t)Cn * Cn * 2);
  unsigned short* q_r    = (unsigned short*)alloc((size_t)Hn * Tn * DHn * 2);
  unsigned short* k_r    = (unsigned short*)alloc((size_t)Hn * Tn * DHn * 2);
  unsigned short* v_s    = (unsigned short*)alloc((size_t)Hn * Tn * DHn * 2);
  unsigned short* pv1    = (unsigned short*)alloc((size_t)Hn * Tn * DHn * 2);
  unsigned short* y_bf   = (unsigned short*)alloc((size_t)Tn * Cn * 2);
  unsigned short* pfrag  = (unsigned short*)alloc((size_t)Hn * (Tn / QBLK) * 4 * 7 * 512 * 2);

  k_prep<<<2816, 256, 0, stream>>>(x, x_bf, Wqkv, WqkvT, Wproj, WprojT);
  k_gemm_bt<2><<<dim3(3 * Cn / 128, Tn / 128), 512, 0, stream>>>(
      x_bf, WqkvT, nullptr, Tn, 3 * Cn, Cn, cosT, sinT, q_r, k_r, v_s);
  k_attn_a<<<dim3(Tn / QBLK, Hn), 256, 0, stream>>>(q_r, k_r, v_s, pv1, pfrag, kap, xiu);
  k_attn_b<<<dim3(Tn / QBLK, Hn), 256, 0, stream>>>(pv1, v_s, pfrag, y_bf, dtl);
  k_gemm_bt<1><<<dim3(Cn / 128, Tn / 128), 512, 0, stream>>>(
      y_bf, WprojT, out, Tn, Cn, Cn, nullptr, nullptr, nullptr, nullptr, nullptr);
}

// Round 7
// 91.095 us; speedup vs baseline: 1.2179x; 1.1050x over previous
//
#include <hip/hip_runtime.h>
#include <hip/hip_bf16.h>

#define Tn 4096
#define Cn 768
#define Hn 12
#define DHn 64
#define BAND 192
#define QBLK 64
#define TJ 256        // BAND + QBLK staged keys per block
#define NTW 13        // 16-key tiles per wave (band window)

typedef __attribute__((ext_vector_type(8))) short short8;
typedef __attribute__((ext_vector_type(4))) short short4v;
typedef __attribute__((ext_vector_type(4))) float f32x4;

__device__ __forceinline__ float b2f(unsigned short u) {
  union { unsigned int i; float f; } z; z.i = ((unsigned int)u) << 16; return z.f;
}
__device__ __forceinline__ unsigned short f2b(float f) {
  union { float f; unsigned int i; } z; z.f = f;
  unsigned int r = z.i + 0x7FFFu + ((z.i >> 16) & 1u);
  return (unsigned short)(r >> 16);
}

// ---------------- prep: f32->bf16 convert + both weight transposes ----------------
__global__ __launch_bounds__(256) void k_prep(const float* __restrict__ x,
                                              unsigned short* __restrict__ x_bf,
                                              const float* __restrict__ Wqkv,
                                              unsigned short* __restrict__ WqkvT,
                                              const float* __restrict__ Wproj,
                                              unsigned short* __restrict__ WprojT) {
  __shared__ float tile[32][33];
  int b = blockIdx.x, tid = threadIdx.x;
  if (b < 512) {
    int n4 = Tn * Cn / 4;
    for (int i = b * 256 + tid; i < n4; i += 512 * 256) {
      float4 v = ((const float4*)x)[i];
      short4v o;
      o.x = (short)f2b(v.x); o.y = (short)f2b(v.y);
      o.z = (short)f2b(v.z); o.w = (short)f2b(v.w);
      ((short4v*)x_bf)[i] = o;
    }
    return;
  }
  const float* W; unsigned short* WT; int N, r;
  if (b < 2240) { r = b - 512; W = Wqkv; WT = WqkvT; N = 3 * Cn; }
  else          { r = b - 2240; W = Wproj; WT = WprojT; N = Cn; }
  int nb = N / 32;
  int n0 = (r % nb) * 32, k0 = (r / nb) * 32;
  int tx = tid & 31, ty = tid >> 5;   // 32 x 8
  for (int rr = ty; rr < 32; rr += 8) tile[rr][tx] = W[(size_t)(k0 + rr) * N + n0 + tx];
  __syncthreads();
  for (int rr = ty; rr < 32; rr += 8) WT[(size_t)(n0 + rr) * Cn + k0 + tx] = f2b(tile[tx][rr]);
}

// ======== shared GEMM machinery: 256Mx128N tile, BK=64, 8 waves (4x2), 2-deep pipeline ========
// LDS per stage: A 256x64 (32KB) + B 128x64 (16KB). Row = 128B = 8 slots of 16B,
// slot swizzle: lds_slot = global_kchunk ^ (row & 7)  (both-sides involution, rule 21).

__device__ __forceinline__ void g_stage(const unsigned short* __restrict__ Ab,
                                        const unsigned short* __restrict__ Bb,
                                        int K, unsigned short* Abuf, unsigned short* Bbuf,
                                        int kt, int tid) {
  int k0 = kt << 6;
#pragma unroll
  for (int it = 0; it < 4; ++it) {           // A: 2048 chunks
    int c = it * 512 + tid;
    int row = c >> 3;
    int kc = (c & 7) ^ (row & 7);
    const unsigned short* ga = Ab + (size_t)row * K + k0 + kc * 8;
    __builtin_amdgcn_global_load_lds((const __attribute__((address_space(1))) void*)ga,
                                     (__attribute__((address_space(3))) void*)(Abuf + c * 8),
                                     16, 0, 0);
  }
#pragma unroll
  for (int it = 0; it < 2; ++it) {           // B: 1024 chunks
    int c = it * 512 + tid;
    int row = c >> 3;
    int kc = (c & 7) ^ (row & 7);
    const unsigned short* gb = Bb + (size_t)row * K + k0 + kc * 8;
    __builtin_amdgcn_global_load_lds((const __attribute__((address_space(1))) void*)gb,
                                     (__attribute__((address_space(3))) void*)(Bbuf + c * 8),
                                     16, 0, 0);
  }
}

#define GEMM_MAIN(K_)                                                                     \
  __shared__ __align__(16) unsigned short Ls[2][384 * 64];                                \
  int tid = threadIdx.x, lane = tid & 63, wave = tid >> 6;                                \
  int lq = lane & 15, g = (lane >> 4) & 3;                                                \
  int wr = wave >> 1, wc = wave & 1;                                                      \
  int nx = gridDim.x;                                                                     \
  int nwg = nx * gridDim.y;                                                               \
  int lid = blockIdx.y * nx + blockIdx.x;                                                 \
  int swz = (lid & 7) * (nwg >> 3) + (lid >> 3);                                          \
  int bx = swz % nx, by = swz / nx;                                                       \
  int m0 = by * 256, n0 = bx * 128;                                                       \
  const unsigned short* Ab = A + (size_t)m0 * (K_);                                       \
  const unsigned short* Bb = BT + (size_t)n0 * (K_);                                      \
  f32x4 acc[4][4] = {};                                                                   \
  const int NK = (K_) >> 6;                                                               \
  g_stage(Ab, Bb, (K_), Ls[0], Ls[0] + 16384, 0, tid);                                    \
  g_stage(Ab, Bb, (K_), Ls[1], Ls[1] + 16384, 1, tid);                                    \
  for (int kt = 0; kt < NK; ++kt) {                                                       \
    if (kt + 1 < NK) asm volatile("s_waitcnt vmcnt(6)" ::: "memory");                     \
    else             asm volatile("s_waitcnt vmcnt(0)" ::: "memory");                     \
    __builtin_amdgcn_s_barrier();                                                         \
    __builtin_amdgcn_sched_barrier(0);                                                    \
    const unsigned short* Ac = Ls[kt & 1];                                                \
    const unsigned short* Bc = Ls[kt & 1] + 16384;                                        \
    _Pragma("unroll")                                                                     \
    for (int kk = 0; kk < 2; ++kk) {                                                      \
      short8 a[4], b[4];                                                                  \
      _Pragma("unroll")                                                                   \
      for (int m = 0; m < 4; ++m) {                                                       \
        int row = wr * 64 + m * 16 + lq;                                                  \
        int s = (kk * 4 + g) ^ (row & 7);                                                 \
        a[m] = *(const short8*)(Ac + row * 64 + s * 8);                                   \
      }                                                                                   \
      _Pragma("unroll")                                                                   \
      for (int n = 0; n < 4; ++n) {                                                       \
        int row = wc * 64 + n * 16 + lq;                                                  \
        int s = (kk * 4 + g) ^ (row & 7);                                                 \
        b[n] = *(const short8*)(Bc + row * 64 + s * 8);                                   \
      }                                                                                   \
      __builtin_amdgcn_s_setprio(1);                                                      \
      _Pragma("unroll")                                                                   \
      for (int m = 0; m < 4; ++m)                                                         \
        _Pragma("unroll")                                                                 \
        for (int n = 0; n < 4; ++n)                                                       \
          acc[m][n] = __builtin_amdgcn_mfma_f32_16x16x32_bf16(a[m], b[n], acc[m][n], 0, 0, 0); \
      __builtin_amdgcn_s_setprio(0);                                                      \
    }                                                                                     \
    __builtin_amdgcn_sched_barrier(0);                                                    \
    __builtin_amdgcn_s_barrier();                                                         \
    if (kt + 2 < NK) g_stage(Ab, Bb, (K_), Ls[kt & 1], Ls[kt & 1] + 16384, kt + 2, tid);  \
  }

// -------- QKV GEMM with fused RoPE + head-split, LDS-staged coalesced epilogue --------
__global__ __launch_bounds__(512, 2) void k_gqkv(const unsigned short* __restrict__ A,
                                                 const unsigned short* __restrict__ BT,
                                                 const float* __restrict__ cosT,
                                                 const float* __restrict__ sinT,
                                                 unsigned short* __restrict__ qout,
                                                 unsigned short* __restrict__ kout,
                                                 unsigned short* __restrict__ vout) {
  GEMM_MAIN(Cn)
  // epilogue: RoPE in-register, scatter to LDS, coalesced 16B stores out
  int col0 = n0 + wc * 64;                 // this wave's 64 cols = one head of q|k|v
  int part = col0 / Cn;
  unsigned short* Lo = (unsigned short*)Ls;   // 256 x 128 bf16 out tile
#pragma unroll
  for (int m = 0; m < 4; ++m)
#pragma unroll
    for (int i = 0; i < 4; ++i) {
      int lr = wr * 64 + m * 16 + g * 4 + i;
      int t = m0 + lr;
#pragma unroll
      for (int n = 0; n < 4; ++n) {
        int d = n * 16 + lq;
        float val = acc[m][n][i];
        if (part < 2) {
          float cv = cosT[t * DHn + d], sv = sinT[t * DHn + d];
          float partner = acc[m][n ^ 2][i];
          val = (n < 2) ? fmaf(-partner, sv, val * cv) : fmaf(partner, sv, val * cv);
        }
        Lo[lr * 128 + wc * 64 + d] = f2b(val);
      }
    }
  __syncthreads();
  // 256x128 tile -> q/k/v [H][T][64]; 16B chunks, coalesced
#pragma unroll
  for (int it = 0; it < 8; ++it) {
    int c = it * 512 + tid;                // 4096 chunks
    int tr = c >> 4, cc = c & 15;
    int cola = n0 + (cc << 3);
    int pp = cola / Cn;
    int h = (cola % Cn) / DHn;
    int d0 = cola % DHn;
    unsigned short* dst = pp == 0 ? qout : (pp == 1 ? kout : vout);
    *(short8*)(dst + ((size_t)h * Tn + (m0 + tr)) * DHn + d0) = *(const short8*)(Lo + tr * 128 + (cc << 3));
  }
}

// -------- proj GEMM, f32 direct-store epilogue --------
__global__ __launch_bounds__(512, 2) void k_gproj(const unsigned short* __restrict__ A,
                                                  const unsigned short* __restrict__ BT,
                                                  float* __restrict__ Cout) {
  GEMM_MAIN(Cn)
  int r0 = m0 + wr * 64 + g * 4;
  int c0 = n0 + wc * 64 + lq;
#pragma unroll
  for (int m = 0; m < 4; ++m)
#pragma unroll
    for (int n = 0; n < 4; ++n)
#pragma unroll
      for (int i = 0; i < 4; ++i)
        Cout[(size_t)(r0 + m * 16 + i) * Cn + c0 + n * 16] = acc[m][n][i];
}

// ---- stage a 256x64 bf16 tile into LDS in 4x16-subtiled layout via global_load_lds ----
// LDS layout: addr(j,d) = (j>>2)*512 + (d>>4)*128 + (j&3)*32 + (d&15)*2   (bytes)
__device__ __forceinline__ void stage_subtiled(const unsigned short* __restrict__ srcHead,
                                               int jt0, unsigned short* lds, int tid, int wave) {
#pragma unroll
  for (int it = 0; it < 8; ++it) {
    int c = it * 256 + tid;                       // 16B chunk index
    int j = jt0 + ((c >> 5) << 2) + ((c & 7) >> 1);
    j = j < 0 ? 0 : j;
    int d0 = (((c >> 3) & 3) << 4) + ((c & 1) << 3);
    const unsigned short* ga = srcHead + (size_t)j * DHn + d0;
    __builtin_amdgcn_global_load_lds((const __attribute__((address_space(1))) void*)ga,
                                     (__attribute__((address_space(3))) void*)(lds + (it * 4 + wave) * 512),
                                     16, 0, 0);
  }
}

// ---- PV: 7 A-frags (P) x subtiled-V tile -> oacc[4] via ds_read_b64_tr_b16 ----
__device__ __forceinline__ void pv_tr(const unsigned short* Vt, const short8* af,
                                      int wave, int lane, f32x4* oacc) {
  int lq = lane & 15, g = lane >> 4;
  unsigned base = (unsigned)(size_t)(const __attribute__((address_space(3))) unsigned short*)Vt;
  unsigned pl = base + lq * 8;
#pragma unroll
  for (int e = 0; e < 7; ++e) {
    int kl = 16 * wave + 32 * e + 8 * g;
    if (kl > TJ - 8) kl = TJ - 8;          // those lanes carry p==0
    unsigned pe = pl + kl * 128;
    unsigned long long rr[8];
#pragma unroll
    for (int dt = 0; dt < 4; ++dt) {
      asm volatile("ds_read_b64_tr_b16 %0, %1" : "=v"(rr[2 * dt]) : "v"(pe + dt * 128));
      asm volatile("ds_read_b64_tr_b16 %0, %1" : "=v"(rr[2 * dt + 1]) : "v"(pe + dt * 128 + 512));
    }
    asm volatile("s_waitcnt lgkmcnt(0)");
    __builtin_amdgcn_sched_barrier(0);
#pragma unroll
    for (int dt = 0; dt < 4; ++dt) {
      union { unsigned long long u[2]; short8 s; } vb;
      vb.u[0] = rr[2 * dt]; vb.u[1] = rr[2 * dt + 1];
      oacc[dt] = __builtin_amdgcn_mfma_f32_16x16x32_bf16(af[e], vb.s, oacc[dt], 0, 0, 0);
    }
  }
}

// ---------------- pass A: QK^T + softmax; write pv1 and normalized P fragments ----------------
__global__ __launch_bounds__(256) void k_attn_a(const unsigned short* __restrict__ qr,
                                                const unsigned short* __restrict__ kr,
                                                const unsigned short* __restrict__ vin,
                                                unsigned short* __restrict__ pv1out,
                                                unsigned short* __restrict__ pfrag,
                                                const float* __restrict__ kap_p,
                                                const float* __restrict__ xi_p) {
  __shared__ unsigned short Ks[TJ * DHn];   // row-major, 16B-unit XOR swizzle per row
  __shared__ unsigned short Vt[TJ * DHn];   // 4x16 subtiled for tr_read
  int tid = threadIdx.x, lane = tid & 63, wave = tid >> 6;
  int lq = lane & 15, g = lane >> 4;
  int i0 = blockIdx.x * QBLK, h = blockIdx.y;
  int jt0 = i0 - BAND;
  const size_t headoff = (size_t)h * Tn * DHn;

  // stage K (swizzled rows, pre-swizzled global source)
  const unsigned short* krh = kr + headoff;
#pragma unroll
  for (int it = 0; it < 8; ++it) {
    int u = it * 256 + tid;
    int row = u >> 3, c8 = u & 7;
    int j = jt0 + row; j = j < 0 ? 0 : j;
    const unsigned short* ga = krh + (size_t)j * DHn + ((c8 ^ (row & 7)) << 3);
    __builtin_amdgcn_global_load_lds((const __attribute__((address_space(1))) void*)ga,
                                     (__attribute__((address_space(3))) void*)((char*)Ks + (size_t)(it * 256 + wave * 64) * 16),
                                     16, 0, 0);
  }
  // stage V subtiled
  stage_subtiled(vin + headoff, jt0, Vt, tid, wave);

  // Q fragments from global
  const unsigned short* qrh = qr + headoff;
  int q0 = i0 + wave * 16;
  short8 qf0 = *(const short8*)(qrh + (size_t)(q0 + lq) * DHn + g * 8);
  short8 qf1 = *(const short8*)(qrh + (size_t)(q0 + lq) * DHn + 32 + g * 8);
  __syncthreads();

  // S^T = K . Q^T over this wave's 13 key tiles
  f32x4 st[NTW];
#pragma unroll
  for (int t = 0; t < NTW; ++t) st[t] = (f32x4){0.f, 0.f, 0.f, 0.f};
#pragma unroll
  for (int t = 0; t < NTW; ++t) {
    int row = (wave + t) * 16 + lq;
    const char* kb = (const char*)Ks + row * 128;
    int sw = row & 7;
    short8 ka0 = *(const short8*)(kb + ((g ^ sw) << 4));
    short8 ka1 = *(const short8*)(kb + (((4 + g) ^ sw) << 4));
    st[t] = __builtin_amdgcn_mfma_f32_16x16x32_bf16(ka0, qf0, st[t], 0, 0, 0);
    st[t] = __builtin_amdgcn_mfma_f32_16x16x32_bf16(ka1, qf1, st[t], 0, 0, 0);
  }

  // softmax (log2 domain), lane-local + 2 shfl_xor
  float kap = log1pf(__expf(*kap_p));
  float xi  = log1pf(__expf(*xi_p));
  const float LOG2E = 1.4426950408889634f;
  float sc = 0.125f * LOG2E;
  float c2 = kap / (xi * xi) * LOG2E;
  float db0 = (float)(lq + BAND - 4 * g);
  float jb0 = (float)(jt0 + 16 * wave + 4 * g);
  float m = -3.0e38f;
#pragma unroll
  for (int t = 0; t < NTW; ++t) {
#pragma unroll
    for (int r = 0; r < 4; ++r) {
      float off = (float)(16 * t + r);
      float dist = db0 - off;
      float jv = jb0 + off;
      float l2 = fmaf(dist * dist, -c2, st[t][r] * sc);
      bool bad = (dist < 0.f) || (jv < 0.f);
      l2 = bad ? -3.0e38f : l2;
      st[t][r] = l2;
      m = fmaxf(m, l2);
    }
  }
  m = fmaxf(m, __shfl_xor(m, 16));
  m = fmaxf(m, __shfl_xor(m, 32));
  float sum = 0.f;
#pragma unroll
  for (int t = 0; t < NTW; ++t) {
#pragma unroll
    for (int r = 0; r < 4; ++r) {
      float p = exp2f(st[t][r] - m);
      st[t][r] = p;
      sum += p;
    }
  }
  sum += __shfl_xor(sum, 16);
  sum += __shfl_xor(sum, 32);
  float inv_s = 1.f / sum;

  // pack NORMALIZED P to bf16 pairs
  unsigned int pk0[NTW], pk1[NTW];
#pragma unroll
  for (int t = 0; t < NTW; ++t) {
    pk0[t] = (unsigned int)f2b(st[t][0] * inv_s) | ((unsigned int)f2b(st[t][1] * inv_s) << 16);
    pk1[t] = (unsigned int)f2b(st[t][2] * inv_s) | ((unsigned int)f2b(st[t][3] * inv_s) << 16);
  }

  // redistribute into A-fragments via shfl
  short8 af[7];
  int srcA = lq + (g & 1) * 32;
  int srcB = srcA + 16;
  bool hiT = (g >= 2);
#pragma unroll
  for (int e = 0; e < 7; ++e) {
    unsigned int aA0 = __shfl(pk0[2 * e], srcA);
    unsigned int aA1 = __shfl(pk1[2 * e], srcA);
    unsigned int aB0 = __shfl(pk0[2 * e], srcB);
    unsigned int aB1 = __shfl(pk1[2 * e], srcB);
    unsigned int dw0, dw1, dw2, dw3;
    if (e < 6) {
      unsigned int bA0 = __shfl(pk0[2 * e + 1], srcA);
      unsigned int bA1 = __shfl(pk1[2 * e + 1], srcA);
      unsigned int bB0 = __shfl(pk0[2 * e + 1], srcB);
      unsigned int bB1 = __shfl(pk1[2 * e + 1], srcB);
      dw0 = hiT ? bA0 : aA0; dw1 = hiT ? bA1 : aA1;
      dw2 = hiT ? bB0 : aB0; dw3 = hiT ? bB1 : aB1;
    } else {
      dw0 = hiT ? 0u : aA0; dw1 = hiT ? 0u : aA1;
      dw2 = hiT ? 0u : aB0; dw3 = hiT ? 0u : aB1;
    }
    union { unsigned int u[4]; short8 s; } t2;
    t2.u[0] = dw0; t2.u[1] = dw1; t2.u[2] = dw2; t2.u[3] = dw3;
    af[e] = t2.s;
  }

  // store P fragments (coalesced 16B/lane)
  size_t pfb = ((((size_t)h * (Tn / QBLK) + blockIdx.x) * 4 + wave) * 7) * 512 + (size_t)lane * 8;
#pragma unroll
  for (int e = 0; e < 7; ++e)
    *(short8*)(pfrag + pfb + (size_t)e * 512) = af[e];

  // PV via tr_read
  f32x4 oacc[4];
#pragma unroll
  for (int dt = 0; dt < 4; ++dt) oacc[dt] = (f32x4){0.f, 0.f, 0.f, 0.f};
  pv_tr(Vt, af, wave, lane, oacc);

  // epilogue: row = 4g+r within wave's 16 queries, col = 16dt+lq (already normalized)
#pragma unroll
  for (int dt = 0; dt < 4; ++dt)
#pragma unroll
    for (int r = 0; r < 4; ++r) {
      int i = i0 + 16 * wave + 4 * g + r;
      pv1out[headoff + (size_t)i * DHn + dt * 16 + lq] = f2b(oacc[dt][r]);
    }
}

// ---------------- pass B: pv2 = P @ pv1 (P from stored frags); combine -> y[T][C] ----------------
__global__ __launch_bounds__(256) void k_attn_b(const unsigned short* __restrict__ pv1,
                                                const unsigned short* __restrict__ v0,
                                                const unsigned short* __restrict__ pfrag,
                                                unsigned short* __restrict__ yout,
                                                const float* __restrict__ dt_logit_p) {
  __shared__ unsigned short Vt[TJ * DHn];   // subtiled pv1 tile
  int tid = threadIdx.x, lane = tid & 63, wave = tid >> 6;
  int lq = lane & 15, g = lane >> 4;
  int i0 = blockIdx.x * QBLK, h = blockIdx.y;
  int jt0 = i0 - BAND;
  const size_t headoff = (size_t)h * Tn * DHn;

  stage_subtiled(pv1 + headoff, jt0, Vt, tid, wave);

  // load P fragments
  short8 af[7];
  size_t pfb = ((((size_t)h * (Tn / QBLK) + blockIdx.x) * 4 + wave) * 7) * 512 + (size_t)lane * 8;
#pragma unroll
  for (int e = 0; e < 7; ++e)
    af[e] = *(const short8*)(pfrag + pfb + (size_t)e * 512);
  __syncthreads();

  f32x4 oacc[4];
#pragma unroll
  for (int dt = 0; dt < 4; ++dt) oacc[dt] = (f32x4){0.f, 0.f, 0.f, 0.f};
  pv_tr(Vt, af, wave, lane, oacc);

  float dtv = 1.f / (1.f + __expf(-*dt_logit_p));
  float a1 = dtv, a2 = 0.5f * dtv * dtv;
  float inv3 = 1.f / (1.f + a1 + a2);
  float w0 = inv3, w1 = a1 * inv3, w2 = a2 * inv3;

#pragma unroll
  for (int dt = 0; dt < 4; ++dt)
#pragma unroll
    for (int r = 0; r < 4; ++r) {
      int i = i0 + 16 * wave + 4 * g + r;
      // pv1[i][d] from the staged subtiled tile (row 192 + i-i0)
      int j = 192 + 16 * wave + 4 * g + r;
      unsigned boff = (unsigned)((j >> 2) * 512 + dt * 128 + (j & 3) * 32 + lq * 2);
      float p1 = b2f(*(const unsigned short*)((const char*)Vt + boff));
      float vv = b2f(v0[headoff + (size_t)i * DHn + dt * 16 + lq]);
      float yv = w0 * vv + w1 * p1 + w2 * oacc[dt][r];
      yout[(size_t)i * Cn + h * DHn + dt * 16 + lq] = f2b(yv);
    }
}

extern "C" void kernel_launch(void* const* d_in, const int* in_sizes, int n_in,
                              void* d_out, int out_size, void* d_ws, size_t ws_size,
                              hipStream_t stream) {
  (void)in_sizes; (void)n_in; (void)out_size; (void)ws_size;
  const float* x     = (const float*)d_in[0];
  const float* cosT  = (const float*)d_in[1];
  const float* sinT  = (const float*)d_in[2];
  const float* Wqkv  = (const float*)d_in[3];
  const float* Wproj = (const float*)d_in[4];
  const float* dtl   = (const float*)d_in[5];
  const float* kap   = (const float*)d_in[6];
  const float* xiu   = (const float*)d_in[7];
  float* out = (float*)d_out;
  char* ws = (char*)d_ws;
  size_t off = 0;
  auto alloc = [&](size_t bytes) { char* p = ws + off; off += (bytes + 255) & ~(size_t)255; return p; };
  unsigned short* x_bf   = (unsigned short*)alloc((size_t)Tn * Cn * 2);
  unsigned short* WqkvT  = (unsigned short*)alloc((size_t)3 * Cn * Cn * 2);
  unsigned short* WprojT = (unsigned short*)alloc((size_t)Cn * Cn * 2);
  unsigned short* q_r    = (unsigned short*)alloc((size_t)Hn * Tn * DHn * 2);
  unsigned short* k_r    = (unsigned short*)alloc((size_t)Hn * Tn * DHn * 2);
  unsigned short* v_s    = (unsigned short*)alloc((size_t)Hn * Tn * DHn * 2);
  unsigned short* pv1    = (unsigned short*)alloc((size_t)Hn * Tn * DHn * 2);
  unsigned short* y_bf   = (unsigned short*)alloc((size_t)Tn * Cn * 2);
  unsigned short* pfrag  = (unsigned short*)alloc((size_t)Hn * (Tn / QBLK) * 4 * 7 * 512 * 2);

  k_prep<<<2816, 256, 0, stream>>>(x, x_bf, Wqkv, WqkvT, Wproj, WprojT);
  k_gqkv<<<dim3(3 * Cn / 128, Tn / 256), 512, 0, stream>>>(
      x_bf, WqkvT, cosT, sinT, q_r, k_r, v_s);
  k_attn_a<<<dim3(Tn / QBLK, Hn), 256, 0, stream>>>(q_r, k_r, v_s, pv1, pfrag, kap, xiu);
  k_attn_b<<<dim3(Tn / QBLK, Hn), 256, 0, stream>>>(pv1, v_s, pfrag, y_bf, dtl);
  k_gproj<<<dim3(Cn / 128, Tn / 256), 512, 0, stream>>>(y_bf, WprojT, out);
}

// Round 8
// 88.061 us; speedup vs baseline: 1.2599x; 1.0345x over previous
//
#include <hip/hip_runtime.h>
#include <hip/hip_bf16.h>

#define Tn 4096
#define Cn 768
#define Hn 12
#define DHn 64
#define BAND 192
#define QBLK 64
#define TJ 256        // BAND + QBLK staged keys per block
#define NTW 13        // 16-key tiles per wave (band window)

typedef __attribute__((ext_vector_type(8))) short short8;
typedef __attribute__((ext_vector_type(4))) short short4v;
typedef __attribute__((ext_vector_type(4))) float f32x4;

__device__ __forceinline__ float b2f(unsigned short u) {
  union { unsigned int i; float f; } z; z.i = ((unsigned int)u) << 16; return z.f;
}
__device__ __forceinline__ unsigned short f2b(float f) {
  union { float f; unsigned int i; } z; z.f = f;
  unsigned int r = z.i + 0x7FFFu + ((z.i >> 16) & 1u);
  return (unsigned short)(r >> 16);
}

// ---------------- prep: f32->bf16 convert + both weight transposes ----------------
__global__ __launch_bounds__(256) void k_prep(const float* __restrict__ x,
                                              unsigned short* __restrict__ x_bf,
                                              const float* __restrict__ Wqkv,
                                              unsigned short* __restrict__ WqkvT,
                                              const float* __restrict__ Wproj,
                                              unsigned short* __restrict__ WprojT) {
  __shared__ float tile[32][33];
  int b = blockIdx.x, tid = threadIdx.x;
  if (b < 512) {
    int n4 = Tn * Cn / 4;
    for (int i = b * 256 + tid; i < n4; i += 512 * 256) {
      float4 v = ((const float4*)x)[i];
      short4v o;
      o.x = (short)f2b(v.x); o.y = (short)f2b(v.y);
      o.z = (short)f2b(v.z); o.w = (short)f2b(v.w);
      ((short4v*)x_bf)[i] = o;
    }
    return;
  }
  const float* W; unsigned short* WT; int N, r;
  if (b < 2240) { r = b - 512; W = Wqkv; WT = WqkvT; N = 3 * Cn; }
  else          { r = b - 2240; W = Wproj; WT = WprojT; N = Cn; }
  int nb = N / 32;
  int n0 = (r % nb) * 32, k0 = (r / nb) * 32;
  int tx = tid & 31, ty = tid >> 5;   // 32 x 8
  for (int rr = ty; rr < 32; rr += 8) tile[rr][tx] = W[(size_t)(k0 + rr) * N + n0 + tx];
  __syncthreads();
  for (int rr = ty; rr < 32; rr += 8) WT[(size_t)(n0 + rr) * Cn + k0 + tx] = f2b(tile[tx][rr]);
}

// ======== GEMM: 128x128 tile, BK=64, 4 waves (2x2, 64x64 each), 2-deep pipeline ========
// LDS per stage: A 128x64 (16KB) + B 128x64 (16KB); 2 stages = 64KB -> 2 blocks/CU.
// Row = 128B = 8 slots of 16B; slot swizzle: lds_slot = kchunk ^ (row & 7) (involution, rule 21).

__device__ __forceinline__ void g_stage(const unsigned short* __restrict__ Ab,
                                        const unsigned short* __restrict__ Bb,
                                        int K, unsigned short* Abuf, unsigned short* Bbuf,
                                        int kt, int tid) {
  int k0 = kt << 6;
#pragma unroll
  for (int it = 0; it < 4; ++it) {           // A: 1024 chunks
    int c = it * 256 + tid;
    int row = c >> 3;
    int kc = (c & 7) ^ (row & 7);
    const unsigned short* ga = Ab + (size_t)row * K + k0 + kc * 8;
    __builtin_amdgcn_global_load_lds((const __attribute__((address_space(1))) void*)ga,
                                     (__attribute__((address_space(3))) void*)(Abuf + c * 8),
                                     16, 0, 0);
  }
#pragma unroll
  for (int it = 0; it < 4; ++it) {           // B: 1024 chunks
    int c = it * 256 + tid;
    int row = c >> 3;
    int kc = (c & 7) ^ (row & 7);
    const unsigned short* gb = Bb + (size_t)row * K + k0 + kc * 8;
    __builtin_amdgcn_global_load_lds((const __attribute__((address_space(1))) void*)gb,
                                     (__attribute__((address_space(3))) void*)(Bbuf + c * 8),
                                     16, 0, 0);
  }
}

#define GEMM_MAIN(K_)                                                                     \
  __shared__ __align__(16) unsigned short Ls[2][256 * 64];                                \
  int tid = threadIdx.x, lane = tid & 63, wave = tid >> 6;                                \
  int lq = lane & 15, g = (lane >> 4) & 3;                                                \
  int wr = wave >> 1, wc = wave & 1;                                                      \
  int nx = gridDim.x;                                                                     \
  int nwg = nx * gridDim.y;                                                               \
  int lid = blockIdx.y * nx + blockIdx.x;                                                 \
  int swz = (lid & 7) * (nwg >> 3) + (lid >> 3);                                          \
  int bx = swz % nx, by = swz / nx;                                                       \
  int m0 = by * 128, n0 = bx * 128;                                                       \
  const unsigned short* Ab = A + (size_t)m0 * (K_);                                       \
  const unsigned short* Bb = BT + (size_t)n0 * (K_);                                      \
  f32x4 acc[4][4] = {};                                                                   \
  const int NK = (K_) >> 6;                                                               \
  g_stage(Ab, Bb, (K_), Ls[0], Ls[0] + 8192, 0, tid);                                     \
  g_stage(Ab, Bb, (K_), Ls[1], Ls[1] + 8192, 1, tid);                                     \
  for (int kt = 0; kt < NK; ++kt) {                                                       \
    if (kt + 1 < NK) asm volatile("s_waitcnt vmcnt(8)" ::: "memory");                     \
    else             asm volatile("s_waitcnt vmcnt(0)" ::: "memory");                     \
    __builtin_amdgcn_s_barrier();                                                         \
    __builtin_amdgcn_sched_barrier(0);                                                    \
    const unsigned short* Ac = Ls[kt & 1];                                                \
    const unsigned short* Bc = Ls[kt & 1] + 8192;                                         \
    _Pragma("unroll")                                                                     \
    for (int kk = 0; kk < 2; ++kk) {                                                      \
      short8 a[4], b[4];                                                                  \
      _Pragma("unroll")                                                                   \
      for (int m = 0; m < 4; ++m) {                                                       \
        int row = wr * 64 + m * 16 + lq;                                                  \
        int s = (kk * 4 + g) ^ (row & 7);                                                 \
        a[m] = *(const short8*)(Ac + row * 64 + s * 8);                                   \
      }                                                                                   \
      _Pragma("unroll")                                                                   \
      for (int n = 0; n < 4; ++n) {                                                       \
        int row = wc * 64 + n * 16 + lq;                                                  \
        int s = (kk * 4 + g) ^ (row & 7);                                                 \
        b[n] = *(const short8*)(Bc + row * 64 + s * 8);                                   \
      }                                                                                   \
      __builtin_amdgcn_s_setprio(1);                                                      \
      _Pragma("unroll")                                                                   \
      for (int m = 0; m < 4; ++m)                                                         \
        _Pragma("unroll")                                                                 \
        for (int n = 0; n < 4; ++n)                                                       \
          acc[m][n] = __builtin_amdgcn_mfma_f32_16x16x32_bf16(a[m], b[n], acc[m][n], 0, 0, 0); \
      __builtin_amdgcn_s_setprio(0);                                                      \
    }                                                                                     \
    __builtin_amdgcn_sched_barrier(0);                                                    \
    __builtin_amdgcn_s_barrier();                                                         \
    if (kt + 2 < NK) g_stage(Ab, Bb, (K_), Ls[kt & 1], Ls[kt & 1] + 8192, kt + 2, tid);   \
  }

// -------- QKV GEMM with fused RoPE + head-split, LDS-staged coalesced epilogue --------
__global__ __launch_bounds__(256, 2) void k_gqkv(const unsigned short* __restrict__ A,
                                                 const unsigned short* __restrict__ BT,
                                                 const float* __restrict__ cosT,
                                                 const float* __restrict__ sinT,
                                                 unsigned short* __restrict__ qout,
                                                 unsigned short* __restrict__ kout,
                                                 unsigned short* __restrict__ vout) {
  GEMM_MAIN(Cn)
  // epilogue: RoPE in-register, scatter to LDS, coalesced 16B stores out
  int col0 = n0 + wc * 64;                 // this wave's 64 cols = one head of q|k|v
  int part = col0 / Cn;
  unsigned short* Lo = (unsigned short*)Ls;   // 128 x 128 bf16 out tile
#pragma unroll
  for (int m = 0; m < 4; ++m)
#pragma unroll
    for (int i = 0; i < 4; ++i) {
      int lr = wr * 64 + m * 16 + g * 4 + i;
      int t = m0 + lr;
#pragma unroll
      for (int n = 0; n < 4; ++n) {
        int d = n * 16 + lq;
        float val = acc[m][n][i];
        if (part < 2) {
          float cv = cosT[t * DHn + d], sv = sinT[t * DHn + d];
          float partner = acc[m][n ^ 2][i];
          val = (n < 2) ? fmaf(-partner, sv, val * cv) : fmaf(partner, sv, val * cv);
        }
        Lo[lr * 128 + wc * 64 + d] = f2b(val);
      }
    }
  __syncthreads();
  // 128x128 tile -> q/k/v [H][T][64]; 16B chunks, coalesced
#pragma unroll
  for (int it = 0; it < 8; ++it) {
    int c = it * 256 + tid;                // 2048 chunks
    int tr = c >> 4, cc = c & 15;
    int cola = n0 + (cc << 3);
    int pp = cola / Cn;
    int h = (cola % Cn) / DHn;
    int d0 = cola % DHn;
    unsigned short* dst = pp == 0 ? qout : (pp == 1 ? kout : vout);
    *(short8*)(dst + ((size_t)h * Tn + (m0 + tr)) * DHn + d0) = *(const short8*)(Lo + tr * 128 + (cc << 3));
  }
}

// -------- proj GEMM, f32 direct-store epilogue --------
__global__ __launch_bounds__(256, 2) void k_gproj(const unsigned short* __restrict__ A,
                                                  const unsigned short* __restrict__ BT,
                                                  float* __restrict__ Cout) {
  GEMM_MAIN(Cn)
  int r0 = m0 + wr * 64 + g * 4;
  int c0 = n0 + wc * 64 + lq;
#pragma unroll
  for (int m = 0; m < 4; ++m)
#pragma unroll
    for (int n = 0; n < 4; ++n)
#pragma unroll
      for (int i = 0; i < 4; ++i)
        Cout[(size_t)(r0 + m * 16 + i) * Cn + c0 + n * 16] = acc[m][n][i];
}

// ---- stage a 256x64 bf16 tile into LDS in 4x16-subtiled layout via global_load_lds ----
// LDS layout: addr(j,d) = (j>>2)*512 + (d>>4)*128 + (j&3)*32 + (d&15)*2   (bytes)
__device__ __forceinline__ void stage_subtiled(const unsigned short* __restrict__ srcHead,
                                               int jt0, unsigned short* lds, int tid, int wave) {
#pragma unroll
  for (int it = 0; it < 8; ++it) {
    int c = it * 256 + tid;                       // 16B chunk index
    int j = jt0 + ((c >> 5) << 2) + ((c & 7) >> 1);
    j = j < 0 ? 0 : j;
    int d0 = (((c >> 3) & 3) << 4) + ((c & 1) << 3);
    const unsigned short* ga = srcHead + (size_t)j * DHn + d0;
    __builtin_amdgcn_global_load_lds((const __attribute__((address_space(1))) void*)ga,
                                     (__attribute__((address_space(3))) void*)(lds + (it * 4 + wave) * 512),
                                     16, 0, 0);
  }
}

// ---- PV: 7 A-frags (P) x subtiled-V tile -> oacc[4] via ds_read_b64_tr_b16 ----
__device__ __forceinline__ void pv_tr(const unsigned short* Vt, const short8* af,
                                      int wave, int lane, f32x4* oacc) {
  int lq = lane & 15, g = lane >> 4;
  unsigned base = (unsigned)(size_t)(const __attribute__((address_space(3))) unsigned short*)Vt;
  unsigned pl = base + lq * 8;
#pragma unroll
  for (int e = 0; e < 7; ++e) {
    int kl = 16 * wave + 32 * e + 8 * g;
    if (kl > TJ - 8) kl = TJ - 8;          // those lanes carry p==0
    unsigned pe = pl + kl * 128;
    unsigned long long rr[8];
#pragma unroll
    for (int dt = 0; dt < 4; ++dt) {
      asm volatile("ds_read_b64_tr_b16 %0, %1" : "=v"(rr[2 * dt]) : "v"(pe + dt * 128));
      asm volatile("ds_read_b64_tr_b16 %0, %1" : "=v"(rr[2 * dt + 1]) : "v"(pe + dt * 128 + 512));
    }
    asm volatile("s_waitcnt lgkmcnt(0)");
    __builtin_amdgcn_sched_barrier(0);
#pragma unroll
    for (int dt = 0; dt < 4; ++dt) {
      union { unsigned long long u[2]; short8 s; } vb;
      vb.u[0] = rr[2 * dt]; vb.u[1] = rr[2 * dt + 1];
      oacc[dt] = __builtin_amdgcn_mfma_f32_16x16x32_bf16(af[e], vb.s, oacc[dt], 0, 0, 0);
    }
  }
}

// ---------------- pass A: QK^T + softmax; write pv1 and normalized P fragments ----------------
__global__ __launch_bounds__(256) void k_attn_a(const unsigned short* __restrict__ qr,
                                                const unsigned short* __restrict__ kr,
                                                const unsigned short* __restrict__ vin,
                                                unsigned short* __restrict__ pv1out,
                                                unsigned short* __restrict__ pfrag,
                                                const float* __restrict__ kap_p,
                                                const float* __restrict__ xi_p) {
  __shared__ unsigned short Ks[TJ * DHn];   // row-major, 16B-unit XOR swizzle per row
  __shared__ unsigned short Vt[TJ * DHn];   // 4x16 subtiled for tr_read
  int tid = threadIdx.x, lane = tid & 63, wave = tid >> 6;
  int lq = lane & 15, g = lane >> 4;
  int i0 = blockIdx.x * QBLK, h = blockIdx.y;
  int jt0 = i0 - BAND;
  const size_t headoff = (size_t)h * Tn * DHn;

  // stage K (swizzled rows, pre-swizzled global source)
  const unsigned short* krh = kr + headoff;
#pragma unroll
  for (int it = 0; it < 8; ++it) {
    int u = it * 256 + tid;
    int row = u >> 3, c8 = u & 7;
    int j = jt0 + row; j = j < 0 ? 0 : j;
    const unsigned short* ga = krh + (size_t)j * DHn + ((c8 ^ (row & 7)) << 3);
    __builtin_amdgcn_global_load_lds((const __attribute__((address_space(1))) void*)ga,
                                     (__attribute__((address_space(3))) void*)((char*)Ks + (size_t)(it * 256 + wave * 64) * 16),
                                     16, 0, 0);
  }
  // stage V subtiled
  stage_subtiled(vin + headoff, jt0, Vt, tid, wave);

  // Q fragments from global
  const unsigned short* qrh = qr + headoff;
  int q0 = i0 + wave * 16;
  short8 qf0 = *(const short8*)(qrh + (size_t)(q0 + lq) * DHn + g * 8);
  short8 qf1 = *(const short8*)(qrh + (size_t)(q0 + lq) * DHn + 32 + g * 8);
  __syncthreads();

  // S^T = K . Q^T over this wave's 13 key tiles
  f32x4 st[NTW];
#pragma unroll
  for (int t = 0; t < NTW; ++t) st[t] = (f32x4){0.f, 0.f, 0.f, 0.f};
#pragma unroll
  for (int t = 0; t < NTW; ++t) {
    int row = (wave + t) * 16 + lq;
    const char* kb = (const char*)Ks + row * 128;
    int sw = row & 7;
    short8 ka0 = *(const short8*)(kb + ((g ^ sw) << 4));
    short8 ka1 = *(const short8*)(kb + (((4 + g) ^ sw) << 4));
    st[t] = __builtin_amdgcn_mfma_f32_16x16x32_bf16(ka0, qf0, st[t], 0, 0, 0);
    st[t] = __builtin_amdgcn_mfma_f32_16x16x32_bf16(ka1, qf1, st[t], 0, 0, 0);
  }

  // softmax (log2 domain), lane-local + 2 shfl_xor
  float kap = log1pf(__expf(*kap_p));
  float xi  = log1pf(__expf(*xi_p));
  const float LOG2E = 1.4426950408889634f;
  float sc = 0.125f * LOG2E;
  float c2 = kap / (xi * xi) * LOG2E;
  float db0 = (float)(lq + BAND - 4 * g);
  float jb0 = (float)(jt0 + 16 * wave + 4 * g);
  float m = -3.0e38f;
#pragma unroll
  for (int t = 0; t < NTW; ++t) {
#pragma unroll
    for (int r = 0; r < 4; ++r) {
      float off = (float)(16 * t + r);
      float dist = db0 - off;
      float jv = jb0 + off;
      float l2 = fmaf(dist * dist, -c2, st[t][r] * sc);
      bool bad = (dist < 0.f) || (jv < 0.f);
      l2 = bad ? -3.0e38f : l2;
      st[t][r] = l2;
      m = fmaxf(m, l2);
    }
  }
  m = fmaxf(m, __shfl_xor(m, 16));
  m = fmaxf(m, __shfl_xor(m, 32));
  float sum = 0.f;
#pragma unroll
  for (int t = 0; t < NTW; ++t) {
#pragma unroll
    for (int r = 0; r < 4; ++r) {
      float p = exp2f(st[t][r] - m);
      st[t][r] = p;
      sum += p;
    }
  }
  sum += __shfl_xor(sum, 16);
  sum += __shfl_xor(sum, 32);
  float inv_s = 1.f / sum;

  // pack NORMALIZED P to bf16 pairs
  unsigned int pk0[NTW], pk1[NTW];
#pragma unroll
  for (int t = 0; t < NTW; ++t) {
    pk0[t] = (unsigned int)f2b(st[t][0] * inv_s) | ((unsigned int)f2b(st[t][1] * inv_s) << 16);
    pk1[t] = (unsigned int)f2b(st[t][2] * inv_s) | ((unsigned int)f2b(st[t][3] * inv_s) << 16);
  }

  // redistribute into A-fragments via shfl
  short8 af[7];
  int srcA = lq + (g & 1) * 32;
  int srcB = srcA + 16;
  bool hiT = (g >= 2);
#pragma unroll
  for (int e = 0; e < 7; ++e) {
    unsigned int aA0 = __shfl(pk0[2 * e], srcA);
    unsigned int aA1 = __shfl(pk1[2 * e], srcA);
    unsigned int aB0 = __shfl(pk0[2 * e], srcB);
    unsigned int aB1 = __shfl(pk1[2 * e], srcB);
    unsigned int dw0, dw1, dw2, dw3;
    if (e < 6) {
      unsigned int bA0 = __shfl(pk0[2 * e + 1], srcA);
      unsigned int bA1 = __shfl(pk1[2 * e + 1], srcA);
      unsigned int bB0 = __shfl(pk0[2 * e + 1], srcB);
      unsigned int bB1 = __shfl(pk1[2 * e + 1], srcB);
      dw0 = hiT ? bA0 : aA0; dw1 = hiT ? bA1 : aA1;
      dw2 = hiT ? bB0 : aB0; dw3 = hiT ? bB1 : aB1;
    } else {
      dw0 = hiT ? 0u : aA0; dw1 = hiT ? 0u : aA1;
      dw2 = hiT ? 0u : aB0; dw3 = hiT ? 0u : aB1;
    }
    union { unsigned int u[4]; short8 s; } t2;
    t2.u[0] = dw0; t2.u[1] = dw1; t2.u[2] = dw2; t2.u[3] = dw3;
    af[e] = t2.s;
  }

  // store P fragments (coalesced 16B/lane)
  size_t pfb = ((((size_t)h * (Tn / QBLK) + blockIdx.x) * 4 + wave) * 7) * 512 + (size_t)lane * 8;
#pragma unroll
  for (int e = 0; e < 7; ++e)
    *(short8*)(pfrag + pfb + (size_t)e * 512) = af[e];

  // PV via tr_read
  f32x4 oacc[4];
#pragma unroll
  for (int dt = 0; dt < 4; ++dt) oacc[dt] = (f32x4){0.f, 0.f, 0.f, 0.f};
  pv_tr(Vt, af, wave, lane, oacc);

  // epilogue: row = 4g+r within wave's 16 queries, col = 16dt+lq (already normalized)
#pragma unroll
  for (int dt = 0; dt < 4; ++dt)
#pragma unroll
    for (int r = 0; r < 4; ++r) {
      int i = i0 + 16 * wave + 4 * g + r;
      pv1out[headoff + (size_t)i * DHn + dt * 16 + lq] = f2b(oacc[dt][r]);
    }
}

// ---------------- pass B: pv2 = P @ pv1 (P from stored frags); combine -> y[T][C] ----------------
__global__ __launch_bounds__(256) void k_attn_b(const unsigned short* __restrict__ pv1,
                                                const unsigned short* __restrict__ v0,
                                                const unsigned short* __restrict__ pfrag,
                                                unsigned short* __restrict__ yout,
                                                const float* __restrict__ dt_logit_p) {
  __shared__ unsigned short Vt[TJ * DHn];   // subtiled pv1 tile
  int tid = threadIdx.x, lane = tid & 63, wave = tid >> 6;
  int lq = lane & 15, g = lane >> 4;
  int i0 = blockIdx.x * QBLK, h = blockIdx.y;
  int jt0 = i0 - BAND;
  const size_t headoff = (size_t)h * Tn * DHn;

  stage_subtiled(pv1 + headoff, jt0, Vt, tid, wave);

  // load P fragments
  short8 af[7];
  size_t pfb = ((((size_t)h * (Tn / QBLK) + blockIdx.x) * 4 + wave) * 7) * 512 + (size_t)lane * 8;
#pragma unroll
  for (int e = 0; e < 7; ++e)
    af[e] = *(const short8*)(pfrag + pfb + (size_t)e * 512);
  __syncthreads();

  f32x4 oacc[4];
#pragma unroll
  for (int dt = 0; dt < 4; ++dt) oacc[dt] = (f32x4){0.f, 0.f, 0.f, 0.f};
  pv_tr(Vt, af, wave, lane, oacc);

  float dtv = 1.f / (1.f + __expf(-*dt_logit_p));
  float a1 = dtv, a2 = 0.5f * dtv * dtv;
  float inv3 = 1.f / (1.f + a1 + a2);
  float w0 = inv3, w1 = a1 * inv3, w2 = a2 * inv3;

#pragma unroll
  for (int dt = 0; dt < 4; ++dt)
#pragma unroll
    for (int r = 0; r < 4; ++r) {
      int i = i0 + 16 * wave + 4 * g + r;
      // pv1[i][d] from the staged subtiled tile (row 192 + i-i0)
      int j = 192 + 16 * wave + 4 * g + r;
      unsigned boff = (unsigned)((j >> 2) * 512 + dt * 128 + (j & 3) * 32 + lq * 2);
      float p1 = b2f(*(const unsigned short*)((const char*)Vt + boff));
      float vv = b2f(v0[headoff + (size_t)i * DHn + dt * 16 + lq]);
      float yv = w0 * vv + w1 * p1 + w2 * oacc[dt][r];
      yout[(size_t)i * Cn + h * DHn + dt * 16 + lq] = f2b(yv);
    }
}

extern "C" void kernel_launch(void* const* d_in, const int* in_sizes, int n_in,
                              void* d_out, int out_size, void* d_ws, size_t ws_size,
                              hipStream_t stream) {
  (void)in_sizes; (void)n_in; (void)out_size; (void)ws_size;
  const float* x     = (const float*)d_in[0];
  const float* cosT  = (const float*)d_in[1];
  const float* sinT  = (const float*)d_in[2];
  const float* Wqkv  = (const float*)d_in[3];
  const float* Wproj = (const float*)d_in[4];
  const float* dtl   = (const float*)d_in[5];
  const float* kap   = (const float*)d_in[6];
  const float* xiu   = (const float*)d_in[7];
  float* out = (float*)d_out;
  char* ws = (char*)d_ws;
  size_t off = 0;
  auto alloc = [&](size_t bytes) { char* p = ws + off; off += (bytes + 255) & ~(size_t)255; return p; };
  unsigned short* x_bf   = (unsigned short*)alloc((size_t)Tn * Cn * 2);
  unsigned short* WqkvT  = (unsigned short*)alloc((size_t)3 * Cn * Cn * 2);
  unsigned short* WprojT = (unsigned short*)alloc((size_t)Cn * Cn * 2);
  unsigned short* q_r    = (unsigned short*)alloc((size_t)Hn * Tn * DHn * 2);
  unsigned short* k_r    = (unsigned short*)alloc((size_t)Hn * Tn * DHn * 2);
  unsigned short* v_s    = (unsigned short*)alloc((size_t)Hn * Tn * DHn * 2);
  unsigned short* pv1    = (unsigned short*)alloc((size_t)Hn * Tn * DHn * 2);
  unsigned short* y_bf   = (unsigned short*)alloc((size_t)Tn * Cn * 2);
  unsigned short* pfrag  = (unsigned short*)alloc((size_t)Hn * (Tn / QBLK) * 4 * 7 * 512 * 2);

  k_prep<<<2816, 256, 0, stream>>>(x, x_bf, Wqkv, WqkvT, Wproj, WprojT);
  k_gqkv<<<dim3(3 * Cn / 128, Tn / 128), 256, 0, stream>>>(
      x_bf, WqkvT, cosT, sinT, q_r, k_r, v_s);
  k_attn_a<<<dim3(Tn / QBLK, Hn), 256, 0, stream>>>(q_r, k_r, v_s, pv1, pfrag, kap, xiu);
  k_attn_b<<<dim3(Tn / QBLK, Hn), 256, 0, stream>>>(pv1, v_s, pfrag, y_bf, dtl);
  k_gproj<<<dim3(Cn / 128, Tn / 128), 256, 0, stream>>>(y_bf, WprojT, out);
}